// Round 1
// baseline (5433.490 us; speedup 1.0000x reference)
//
#include <hip/hip_runtime.h>
#include <hip/hip_bf16.h>
#include <math.h>

#define DIM 64

typedef __attribute__((ext_vector_type(8))) short short8;
typedef __attribute__((ext_vector_type(4))) float f32x4;

__device__ __forceinline__ short f2bf(float f) {
    unsigned u = __float_as_uint(f);
    unsigned r = (u + 0x7fffu + ((u >> 16) & 1u)) >> 16;   // RNE, no NaN inputs
    return (short)r;
}
__device__ __forceinline__ float bf2f(short s) {
    return __uint_as_float(((unsigned)(unsigned short)s) << 16);
}

// ---------------- CSR build ----------------

__global__ void khist(const int* __restrict__ ei, int E, int* __restrict__ cnt) {
    int e = blockIdx.x * blockDim.x + threadIdx.x;
    if (e < E) atomicAdd(&cnt[ei[E + e]], 1);
}

__global__ void kscan1(const int* __restrict__ cnt, int N,
                       int* __restrict__ rs, int* __restrict__ bsum) {
    __shared__ int sm[512];
    int t = threadIdx.x;
    int i = blockIdx.x * 512 + t;
    int v = (i < N) ? cnt[i] : 0;
    sm[t] = v;
    __syncthreads();
    for (int off = 1; off < 512; off <<= 1) {
        int add = (t >= off) ? sm[t - off] : 0;
        __syncthreads();
        sm[t] += add;
        __syncthreads();
    }
    int inc = sm[t];
    if (i < N) rs[i] = inc - v;              // local exclusive
    if (t == 511) bsum[blockIdx.x] = inc;    // block total
}

__global__ void kscan2(int* __restrict__ bsum, int nb) {
    __shared__ int sm[256];
    int t = threadIdx.x;
    int v = (t < nb) ? bsum[t] : 0;
    sm[t] = v;
    __syncthreads();
    for (int off = 1; off < 256; off <<= 1) {
        int add = (t >= off) ? sm[t - off] : 0;
        __syncthreads();
        sm[t] += add;
        __syncthreads();
    }
    if (t < nb) bsum[t] = sm[t] - v;         // exclusive
}

__global__ void kscan3(int* __restrict__ rs, int* __restrict__ cur,
                       const int* __restrict__ bsum, int N, int E) {
    int i = blockIdx.x * blockDim.x + threadIdx.x;
    if (i < N) {
        int r = rs[i] + bsum[i >> 9];
        rs[i] = r;
        cur[i] = r;
    }
    if (i == 0) rs[N] = E;
}

__global__ void kscatter(const int* __restrict__ ei, int E,
                         int* __restrict__ cur, int* __restrict__ ssrc) {
    int e = blockIdx.x * blockDim.x + threadIdx.x;
    if (e < E) {
        int d = ei[E + e];
        int p = atomicAdd(&cur[d], 1);
        ssrc[p] = ei[e];
    }
}

// ---------------- weight prep: B[k][j] -> MFMA B-fragment order, bf16 hi/lo ----------------
// B[k][j], k in [0,128): k<64 -> Wl[j][k]; k>=64 -> Wr[j][k-64]
// fragment: blk = ((layer*4+s)*4+t)*2 + hl; element [lane][i]: k = s*32+(lane>>4)*8+i, j = t*16+(lane&15)

__global__ void kprepw(const float* __restrict__ Wl, const float* __restrict__ Wr,
                       short* __restrict__ Bf) {
    int id = blockIdx.x * blockDim.x + threadIdx.x;
    if (id >= 6 * 4 * 4 * 64 * 8) return;
    int i = id & 7;
    int lane = (id >> 3) & 63;
    int t = (id >> 9) & 3;
    int s = (id >> 11) & 3;
    int layer = id >> 13;
    int k = s * 32 + (lane >> 4) * 8 + i;
    int j = t * 16 + (lane & 15);
    float v = (k < 64) ? Wl[(layer * 64 + j) * 64 + k]
                       : Wr[(layer * 64 + j) * 64 + (k - 64)];
    short hi = f2bf(v);
    short lo = f2bf(v - bf2f(hi));
    int blk = ((layer * 4 + s) * 4 + t) * 2;
    int base = blk * 512 + lane * 8 + i;
    Bf[base] = hi;          // hl = 0
    Bf[base + 512] = lo;    // hl = 1
}

// ---------------- aggregation: one wave per node, lane = feature ----------------

__global__ void kagg(const float* __restrict__ hin, const int* __restrict__ rs,
                     const int* __restrict__ ssrc, float* __restrict__ agg, int N) {
    int w = (blockIdx.x * blockDim.x + threadIdx.x) >> 6;
    int lane = threadIdx.x & 63;
    if (w >= N) return;
    int beg = rs[w], end = rs[w + 1];
    float m0 = -__builtin_inff(), m1 = m0, m2 = m0, m3 = m0;
    for (int base = beg; base < end; base += 64) {
        int cnt = end - base;
        if (cnt > 64) cnt = 64;
        int sv = (lane < cnt) ? ssrc[base + lane] : 0;   // coalesced edge read
        int j = 0;
        for (; j + 3 < cnt; j += 4) {
            int s0 = __shfl(sv, j), s1 = __shfl(sv, j + 1);
            int s2 = __shfl(sv, j + 2), s3 = __shfl(sv, j + 3);
            float v0 = hin[s0 * DIM + lane];
            float v1 = hin[s1 * DIM + lane];
            float v2 = hin[s2 * DIM + lane];
            float v3 = hin[s3 * DIM + lane];
            m0 = fmaxf(m0, v0); m1 = fmaxf(m1, v1);
            m2 = fmaxf(m2, v2); m3 = fmaxf(m3, v3);
        }
        for (; j < cnt; ++j) {
            int s0 = __shfl(sv, j);
            m0 = fmaxf(m0, hin[s0 * DIM + lane]);
        }
    }
    float m = fmaxf(fmaxf(m0, m1), fmaxf(m2, m3));
    agg[w * DIM + lane] = (end > beg) ? m : 0.0f;   // no in-edges -> 0 (PyG convention)
}

// ---------------- fused GEMM: out = [agg|hin] @ B + bias (+relu), split-bf16 MFMA ----------------

__global__ void __launch_bounds__(256) kgemm(
        const float* __restrict__ agg, const float* __restrict__ hin,
        const short* __restrict__ Bf, const float* __restrict__ bias,
        float* __restrict__ out, int N, int relu) {
    int wave = (blockIdx.x * blockDim.x + threadIdx.x) >> 6;
    int lane = threadIdx.x & 63;
    int ntiles = (N + 15) >> 4;
    if (wave >= ntiles) return;
    int m0 = wave << 4;
    int row = m0 + (lane & 15);
    if (row >= N) row = N - 1;   // clamp for tail tiles (N%16==0 in practice)
    int quad = lane >> 4;

    // A fragments: A[m=lane&15][k = s*32 + quad*8 + i], split hi/lo
    short8 ahi[4], alo[4];
    for (int s = 0; s < 4; ++s) {
        const float* srcp = (s < 2) ? (agg + row * DIM + s * 32 + quad * 8)
                                    : (hin + row * DIM + (s - 2) * 32 + quad * 8);
        f32x4 a0 = *(const f32x4*)(srcp);
        f32x4 a1 = *(const f32x4*)(srcp + 4);
        for (int i = 0; i < 4; ++i) {
            short h0 = f2bf(a0[i]);
            ahi[s][i] = h0;
            alo[s][i] = f2bf(a0[i] - bf2f(h0));
            short h1 = f2bf(a1[i]);
            ahi[s][i + 4] = h1;
            alo[s][i + 4] = f2bf(a1[i] - bf2f(h1));
        }
    }

    f32x4 acc[4] = {{0.f, 0.f, 0.f, 0.f}, {0.f, 0.f, 0.f, 0.f},
                    {0.f, 0.f, 0.f, 0.f}, {0.f, 0.f, 0.f, 0.f}};
    const short8* Bp = (const short8*)Bf;
    for (int s = 0; s < 4; ++s) {
        for (int t = 0; t < 4; ++t) {
            int blk = (s * 4 + t) * 2;
            short8 bhi = Bp[blk * 64 + lane];
            short8 blo = Bp[blk * 64 + 64 + lane];
            acc[t] = __builtin_amdgcn_mfma_f32_16x16x32_bf16(ahi[s], bhi, acc[t], 0, 0, 0);
            acc[t] = __builtin_amdgcn_mfma_f32_16x16x32_bf16(alo[s], bhi, acc[t], 0, 0, 0);
            acc[t] = __builtin_amdgcn_mfma_f32_16x16x32_bf16(ahi[s], blo, acc[t], 0, 0, 0);
        }
    }

    // C/D: col = lane&15, row = quad*4 + reg
    for (int t = 0; t < 4; ++t) {
        int col = t * 16 + (lane & 15);
        float b = bias[col];
        for (int r = 0; r < 4; ++r) {
            int orow = m0 + quad * 4 + r;
            if (orow < N) {
                float v = acc[t][r] + b;
                if (relu) v = fmaxf(v, 0.0f);
                out[orow * DIM + col] = v;
            }
        }
    }
}

// ---------------- host ----------------

extern "C" void kernel_launch(void* const* d_in, const int* in_sizes, int n_in,
                              void* d_out, int out_size, void* d_ws, size_t ws_size,
                              hipStream_t stream) {
    const float* x  = (const float*)d_in[0];
    const int*   ei = (const int*)d_in[1];
    const float* Wl = (const float*)d_in[2];
    const float* bl = (const float*)d_in[3];
    const float* Wr = (const float*)d_in[4];
    int N = in_sizes[0] / DIM;
    int E = in_sizes[1] / 2;

    size_t nd = (size_t)N * DIM;
    float* hA   = (float*)d_ws;
    float* hB   = hA + nd;
    float* agg  = hB + nd;
    int*   rs   = (int*)(agg + nd);      // N+1 used, N+4 reserved (keeps 16B alignment)
    int*   cur  = rs + (N + 4);
    int*   ssrc = cur + N;
    int*   bsum = ssrc + E;              // 2048 reserved
    short* Bf   = (short*)(bsum + 2048); // 6 layers * 16384 shorts

    hipMemsetAsync(cur, 0, (size_t)N * sizeof(int), stream);
    khist<<<(E + 255) / 256, 256, 0, stream>>>(ei, E, cur);
    int nb1 = (N + 511) / 512;
    kscan1<<<nb1, 512, 0, stream>>>(cur, N, rs, bsum);
    kscan2<<<1, 256, 0, stream>>>(bsum, nb1);
    kscan3<<<(N + 255) / 256, 256, 0, stream>>>(rs, cur, bsum, N, E);
    kscatter<<<(E + 255) / 256, 256, 0, stream>>>(ei, E, cur, ssrc);
    kprepw<<<(6 * 4 * 4 * 64 * 8 + 255) / 256, 256, 0, stream>>>(Wl, Wr, Bf);

    const float* hin = x;
    float* bufs[2] = {hA, hB};
    int ntiles = (N + 15) / 16;
    for (int l = 0; l < 6; ++l) {
        float* hout = (l == 5) ? (float*)d_out : bufs[l & 1];
        kagg<<<(N + 3) / 4, 256, 0, stream>>>(hin, rs, ssrc, agg, N);
        kgemm<<<(ntiles + 3) / 4, 256, 0, stream>>>(agg, hin, Bf + l * 16384,
                                                    bl + l * 64, hout, N, l < 5 ? 1 : 0);
        hin = hout;
    }
}

// Round 2
// 741.161 us; speedup vs baseline: 7.3311x; 7.3311x over previous
//
#include <hip/hip_runtime.h>
#include <hip/hip_bf16.h>
#include <math.h>

#define DIM 64

typedef __attribute__((ext_vector_type(8))) short short8;
typedef __attribute__((ext_vector_type(4))) float f32x4;

__device__ __forceinline__ short f2bf(float f) {
    unsigned u = __float_as_uint(f);
    unsigned r = (u + 0x7fffu + ((u >> 16) & 1u)) >> 16;   // RNE, no NaN inputs
    return (short)r;
}
__device__ __forceinline__ float bf2f(short s) {
    return __uint_as_float(((unsigned)(unsigned short)s) << 16);
}

// ---------------- CSR build ----------------

__global__ void khist(const int* __restrict__ ei, int E, int* __restrict__ cnt) {
    int e = blockIdx.x * blockDim.x + threadIdx.x;
    if (e < E) atomicAdd(&cnt[ei[E + e]], 1);
}

__global__ void kscan1(const int* __restrict__ cnt, int N,
                       int* __restrict__ rs, int* __restrict__ bsum) {
    __shared__ int sm[512];
    int t = threadIdx.x;
    int i = blockIdx.x * 512 + t;
    int v = (i < N) ? cnt[i] : 0;
    sm[t] = v;
    __syncthreads();
    for (int off = 1; off < 512; off <<= 1) {
        int add = (t >= off) ? sm[t - off] : 0;
        __syncthreads();
        sm[t] += add;
        __syncthreads();
    }
    int inc = sm[t];
    if (i < N) rs[i] = inc - v;              // local exclusive
    if (t == 511) bsum[blockIdx.x] = inc;    // block total
}

__global__ void kscan2(int* __restrict__ bsum, int nb) {
    __shared__ int sm[256];
    int t = threadIdx.x;
    int v = (t < nb) ? bsum[t] : 0;
    sm[t] = v;
    __syncthreads();
    for (int off = 1; off < 256; off <<= 1) {
        int add = (t >= off) ? sm[t - off] : 0;
        __syncthreads();
        sm[t] += add;
        __syncthreads();
    }
    if (t < nb) bsum[t] = sm[t] - v;         // exclusive
}

__global__ void kscan3(int* __restrict__ rs, int* __restrict__ cur,
                       const int* __restrict__ bsum, int N, int E) {
    int i = blockIdx.x * blockDim.x + threadIdx.x;
    if (i < N) {
        int r = rs[i] + bsum[i >> 9];
        rs[i] = r;
        cur[i] = r;
    }
    if (i == 0) rs[N] = E;
}

__global__ void kscatter(const int* __restrict__ ei, int E,
                         int* __restrict__ cur, int* __restrict__ ssrc) {
    int e = blockIdx.x * blockDim.x + threadIdx.x;
    if (e < E) {
        int d = ei[E + e];
        int p = atomicAdd(&cur[d], 1);
        ssrc[p] = ei[e];
    }
}

// ---------------- weight prep: B[k][j] -> MFMA B-fragment order, bf16 hi/lo ----------------
// B[k][j], k in [0,128): k<64 -> Wl[j][k]; k>=64 -> Wr[j][k-64]
// fragment: blk = ((layer*4+s)*4+t)*2 + hl; element [lane][i]: k = s*32+(lane>>4)*8+i, j = t*16+(lane&15)

__global__ void kprepw(const float* __restrict__ Wl, const float* __restrict__ Wr,
                       short* __restrict__ Bf) {
    int id = blockIdx.x * blockDim.x + threadIdx.x;
    if (id >= 6 * 4 * 4 * 64 * 8) return;
    int i = id & 7;
    int lane = (id >> 3) & 63;
    int t = (id >> 9) & 3;
    int s = (id >> 11) & 3;
    int layer = id >> 13;
    int k = s * 32 + (lane >> 4) * 8 + i;
    int j = t * 16 + (lane & 15);
    float v = (k < 64) ? Wl[(layer * 64 + j) * 64 + k]
                       : Wr[(layer * 64 + j) * 64 + (k - 64)];
    short hi = f2bf(v);
    short lo = f2bf(v - bf2f(hi));
    int blk = ((layer * 4 + s) * 4 + t) * 2;
    int base = blk * 512 + lane * 8 + i;
    Bf[base] = hi;          // hl = 0
    Bf[base + 512] = lo;    // hl = 1
}

// ---------------- aggregation: one wave per node, lane = feature ----------------

__global__ void kagg(const float* __restrict__ hin, const int* __restrict__ rs,
                     const int* __restrict__ ssrc, float* __restrict__ agg, int N) {
    int w = (blockIdx.x * blockDim.x + threadIdx.x) >> 6;
    int lane = threadIdx.x & 63;
    if (w >= N) return;
    int beg = rs[w], end = rs[w + 1];
    float m0 = -__builtin_inff(), m1 = m0, m2 = m0, m3 = m0;
    for (int base = beg; base < end; base += 64) {
        int cnt = end - base;
        if (cnt > 64) cnt = 64;
        int sv = (lane < cnt) ? ssrc[base + lane] : 0;   // coalesced edge read
        int j = 0;
        for (; j + 3 < cnt; j += 4) {
            int s0 = __shfl(sv, j), s1 = __shfl(sv, j + 1);
            int s2 = __shfl(sv, j + 2), s3 = __shfl(sv, j + 3);
            float v0 = hin[s0 * DIM + lane];
            float v1 = hin[s1 * DIM + lane];
            float v2 = hin[s2 * DIM + lane];
            float v3 = hin[s3 * DIM + lane];
            m0 = fmaxf(m0, v0); m1 = fmaxf(m1, v1);
            m2 = fmaxf(m2, v2); m3 = fmaxf(m3, v3);
        }
        for (; j < cnt; ++j) {
            int s0 = __shfl(sv, j);
            m0 = fmaxf(m0, hin[s0 * DIM + lane]);
        }
    }
    float m = fmaxf(fmaxf(m0, m1), fmaxf(m2, m3));
    agg[w * DIM + lane] = (end > beg) ? m : 0.0f;   // no in-edges -> 0 (PyG convention)
}

// ---------------- fused GEMM: out = [agg|hin] @ B + bias (+relu), split-bf16 MFMA ----------------
// Grid-stride over 16-row tiles; B fragments (32 x short8 = 128 VGPRs) resident per wave.

__device__ __forceinline__ void cvt8(f32x4 a0, f32x4 a1, short8& hi, short8& lo) {
#pragma unroll
    for (int i = 0; i < 4; ++i) {
        short h0 = f2bf(a0[i]);
        hi[i] = h0;
        lo[i] = f2bf(a0[i] - bf2f(h0));
        short h1 = f2bf(a1[i]);
        hi[i + 4] = h1;
        lo[i + 4] = f2bf(a1[i] - bf2f(h1));
    }
}

__global__ void __launch_bounds__(256, 2) kgemm(
        const float* __restrict__ agg, const float* __restrict__ hin,
        const short* __restrict__ Bf, const float* __restrict__ bias,
        float* __restrict__ out, int N, int relu) {
    const int lane = threadIdx.x & 63;
    const int quad = lane >> 4;
    const int lrow = lane & 15;
    const int wv = (blockIdx.x * blockDim.x + threadIdx.x) >> 6;
    const int nwv = (gridDim.x * blockDim.x) >> 6;
    const int ntiles = (N + 15) >> 4;

    // B fragments: hold the whole 128x64 (hi+lo) weight block in registers.
    const short8* __restrict__ Bp = (const short8*)Bf;
    short8 bh[4][4], bl[4][4];
#pragma unroll
    for (int s = 0; s < 4; ++s)
#pragma unroll
        for (int t = 0; t < 4; ++t) {
            int blk = (s * 4 + t) * 2;
            bh[s][t] = Bp[blk * 64 + lane];
            bl[s][t] = Bp[blk * 64 + 64 + lane];
        }

    float bs[4];
#pragma unroll
    for (int t = 0; t < 4; ++t) bs[t] = bias[t * 16 + lrow];

    for (int tile = wv; tile < ntiles; tile += nwv) {
        const int m0 = tile << 4;
        int row = m0 + lrow;
        if (row >= N) row = N - 1;    // never triggers for N%16==0
        const float* pa = agg + (size_t)row * DIM + quad * 8;
        const float* ph = hin + (size_t)row * DIM + quad * 8;
        // batched, independent global loads (8 x 16B)
        f32x4 a0 = *(const f32x4*)(pa);
        f32x4 a1 = *(const f32x4*)(pa + 4);
        f32x4 a2 = *(const f32x4*)(pa + 32);
        f32x4 a3 = *(const f32x4*)(pa + 36);
        f32x4 a4 = *(const f32x4*)(ph);
        f32x4 a5 = *(const f32x4*)(ph + 4);
        f32x4 a6 = *(const f32x4*)(ph + 32);
        f32x4 a7 = *(const f32x4*)(ph + 36);

        short8 ahi[4], alo[4];
        cvt8(a0, a1, ahi[0], alo[0]);
        cvt8(a2, a3, ahi[1], alo[1]);
        cvt8(a4, a5, ahi[2], alo[2]);
        cvt8(a6, a7, ahi[3], alo[3]);

        f32x4 acc[4] = {{0.f, 0.f, 0.f, 0.f}, {0.f, 0.f, 0.f, 0.f},
                        {0.f, 0.f, 0.f, 0.f}, {0.f, 0.f, 0.f, 0.f}};
#pragma unroll
        for (int s = 0; s < 4; ++s) {
#pragma unroll
            for (int t = 0; t < 4; ++t) {
                acc[t] = __builtin_amdgcn_mfma_f32_16x16x32_bf16(ahi[s], bh[s][t], acc[t], 0, 0, 0);
                acc[t] = __builtin_amdgcn_mfma_f32_16x16x32_bf16(alo[s], bh[s][t], acc[t], 0, 0, 0);
                acc[t] = __builtin_amdgcn_mfma_f32_16x16x32_bf16(ahi[s], bl[s][t], acc[t], 0, 0, 0);
            }
        }

        // C/D: col = lane&15, row = quad*4 + reg
#pragma unroll
        for (int t = 0; t < 4; ++t) {
            int col = t * 16 + lrow;
#pragma unroll
            for (int r = 0; r < 4; ++r) {
                int orow = m0 + quad * 4 + r;
                if (orow < N) {
                    float v = acc[t][r] + bs[t];
                    if (relu) v = fmaxf(v, 0.0f);
                    out[(size_t)orow * DIM + col] = v;
                }
            }
        }
    }
}

// ---------------- host ----------------

extern "C" void kernel_launch(void* const* d_in, const int* in_sizes, int n_in,
                              void* d_out, int out_size, void* d_ws, size_t ws_size,
                              hipStream_t stream) {
    const float* x  = (const float*)d_in[0];
    const int*   ei = (const int*)d_in[1];
    const float* Wl = (const float*)d_in[2];
    const float* bl = (const float*)d_in[3];
    const float* Wr = (const float*)d_in[4];
    int N = in_sizes[0] / DIM;
    int E = in_sizes[1] / 2;

    size_t nd = (size_t)N * DIM;
    float* hA   = (float*)d_ws;
    float* hB   = hA + nd;
    float* agg  = hB + nd;
    int*   rs   = (int*)(agg + nd);      // N+1 used, N+4 reserved (keeps 16B alignment)
    int*   cur  = rs + (N + 4);
    int*   ssrc = cur + N;
    int*   bsum = ssrc + E;              // 2048 reserved
    short* Bf   = (short*)(bsum + 2048); // 6 layers * 16384 shorts

    hipMemsetAsync(cur, 0, (size_t)N * sizeof(int), stream);
    khist<<<(E + 255) / 256, 256, 0, stream>>>(ei, E, cur);
    int nb1 = (N + 511) / 512;
    kscan1<<<nb1, 512, 0, stream>>>(cur, N, rs, bsum);
    kscan2<<<1, 256, 0, stream>>>(bsum, nb1);
    kscan3<<<(N + 255) / 256, 256, 0, stream>>>(rs, cur, bsum, N, E);
    kscatter<<<(E + 255) / 256, 256, 0, stream>>>(ei, E, cur, ssrc);
    kprepw<<<(6 * 4 * 4 * 64 * 8 + 255) / 256, 256, 0, stream>>>(Wl, Wr, Bf);

    const float* hin = x;
    float* bufs[2] = {hA, hB};
    for (int l = 0; l < 6; ++l) {
        float* hout = (l == 5) ? (float*)d_out : bufs[l & 1];
        kagg<<<(N + 3) / 4, 256, 0, stream>>>(hin, rs, ssrc, agg, N);
        kgemm<<<512, 256, 0, stream>>>(agg, hin, Bf + l * 16384,
                                       bl + l * 64, hout, N, l < 5 ? 1 : 0);
        hin = hout;
    }
}

// Round 4
// 651.002 us; speedup vs baseline: 8.3463x; 1.1385x over previous
//
#include <hip/hip_runtime.h>
#include <hip/hip_bf16.h>
#include <math.h>

#define DIM 64

typedef __attribute__((ext_vector_type(8))) short short8;
typedef __attribute__((ext_vector_type(4))) float f32x4;

__device__ __forceinline__ short f2bf(float f) {
    unsigned u = __float_as_uint(f);
    unsigned r = (u + 0x7fffu + ((u >> 16) & 1u)) >> 16;   // RNE, no NaN inputs
    return (short)r;
}
__device__ __forceinline__ float bf2f(short s) {
    return __uint_as_float(((unsigned)(unsigned short)s) << 16);
}
__device__ __forceinline__ f32x4 max4(f32x4 a, f32x4 b) {
    f32x4 r;
#pragma unroll
    for (int i = 0; i < 4; ++i) r[i] = fmaxf(a[i], b[i]);
    return r;
}

// ---------------- CSR build ----------------

__global__ void khist(const int* __restrict__ ei, int E, int* __restrict__ cnt) {
    int e = blockIdx.x * blockDim.x + threadIdx.x;
    if (e < E) atomicAdd(&cnt[ei[E + e]], 1);
}

__global__ void kscan1(const int* __restrict__ cnt, int N,
                       int* __restrict__ rs, int* __restrict__ bsum) {
    __shared__ int sm[512];
    int t = threadIdx.x;
    int i = blockIdx.x * 512 + t;
    int v = (i < N) ? cnt[i] : 0;
    sm[t] = v;
    __syncthreads();
    for (int off = 1; off < 512; off <<= 1) {
        int add = (t >= off) ? sm[t - off] : 0;
        __syncthreads();
        sm[t] += add;
        __syncthreads();
    }
    int inc = sm[t];
    if (i < N) rs[i] = inc - v;              // local exclusive
    if (t == 511) bsum[blockIdx.x] = inc;    // block total
}

__global__ void kscan2(int* __restrict__ bsum, int nb) {
    __shared__ int sm[256];
    int t = threadIdx.x;
    int v = (t < nb) ? bsum[t] : 0;
    sm[t] = v;
    __syncthreads();
    for (int off = 1; off < 256; off <<= 1) {
        int add = (t >= off) ? sm[t - off] : 0;
        __syncthreads();
        sm[t] += add;
        __syncthreads();
    }
    if (t < nb) bsum[t] = sm[t] - v;         // exclusive
}

__global__ void kscan3(int* __restrict__ rs, int* __restrict__ cur,
                       const int* __restrict__ bsum, int N, int E) {
    int i = blockIdx.x * blockDim.x + threadIdx.x;
    if (i < N) {
        int r = rs[i] + bsum[i >> 9];
        rs[i] = r;
        cur[i] = r;
    }
    if (i == 0) rs[N] = E;
}

__global__ void kbinit(const int* __restrict__ rs, int* __restrict__ gbc, int N, int NB) {
    int b = blockIdx.x * blockDim.x + threadIdx.x;
    if (b < NB) {
        int idx = b << 9;
        if (idx > N) idx = N;
        gbc[b] = rs[idx];
    }
}

// Pass A: bin (src,dst) pairs by dst>>9 into bucket-contiguous regions of `pairs`.
__global__ void kbin(const int* __restrict__ ei, int E,
                     int* __restrict__ gbc, int2* __restrict__ pairs, int NB) {
    __shared__ int hist[256];
    __shared__ int basep[256];
    const int t = threadIdx.x;
    const int c0 = blockIdx.x * 4096;
    hist[t] = 0;
    __syncthreads();
    int s[16], d[16];
#pragma unroll
    for (int i = 0; i < 16; ++i) {
        int e = c0 + i * 256 + t;
        if (e < E) {
            s[i] = ei[e];
            d[i] = ei[E + e];
            atomicAdd(&hist[d[i] >> 9], 1);
        } else d[i] = -1;
    }
    __syncthreads();
    if (t < NB) {
        basep[t] = atomicAdd(&gbc[t], hist[t]);
        hist[t] = 0;
    }
    __syncthreads();
#pragma unroll
    for (int i = 0; i < 16; ++i) {
        if (d[i] >= 0) {
            int b = d[i] >> 9;
            int off = atomicAdd(&hist[b], 1);
            int2 pr; pr.x = s[i]; pr.y = d[i];
            pairs[basep[b] + off] = pr;
        }
    }
}

// Pass B: scatter within buckets (dst-local 32KB windows -> L2-friendly).
__global__ void kscat2(const int2* __restrict__ pairs, int E,
                       int* __restrict__ cur, int* __restrict__ ssrc) {
    int e = blockIdx.x * blockDim.x + threadIdx.x;
    if (e < E) {
        int2 pr = pairs[e];
        int p = atomicAdd(&cur[pr.y], 1);
        ssrc[p] = pr.x;
    }
}

// ---------------- weight prep: B[k][j] -> MFMA B-fragment order, bf16 hi/lo ----------------

__global__ void kprepw(const float* __restrict__ Wl, const float* __restrict__ Wr,
                       short* __restrict__ Bf) {
    int id = blockIdx.x * blockDim.x + threadIdx.x;
    if (id >= 6 * 4 * 4 * 64 * 8) return;
    int i = id & 7;
    int lane = (id >> 3) & 63;
    int t = (id >> 9) & 3;
    int s = (id >> 11) & 3;
    int layer = id >> 13;
    int k = s * 32 + (lane >> 4) * 8 + i;
    int j = t * 16 + (lane & 15);
    float v = (k < 64) ? Wl[(layer * 64 + j) * 64 + k]
                       : Wr[(layer * 64 + j) * 64 + (k - 64)];
    short hi = f2bf(v);
    short lo = f2bf(v - bf2f(hi));
    int blk = ((layer * 4 + s) * 4 + t) * 2;
    int base = blk * 512 + lane * 8 + i;
    Bf[base] = hi;          // hl = 0
    Bf[base + 512] = lo;    // hl = 1
}

// ---------------- aggregation: one wave per node, 4 rows in flight per load ----------------
// lane = g*16+sub: group g handles edges j+g (mod 4); lane reads float4 at cols [sub*4, sub*4+4)
// NOTE: every __shfl below executes with FULL exec (wave-uniform branches only) —
// divergent __shfl reads from inactive lanes are undefined on CDNA (ds_bpermute).

__global__ void kagg(const float* __restrict__ hin, const int* __restrict__ rs,
                     const int* __restrict__ ssrc, float* __restrict__ agg, int N) {
    int w = (blockIdx.x * blockDim.x + threadIdx.x) >> 6;
    int lane = threadIdx.x & 63;
    if (w >= N) return;
    int g = lane >> 4, sub = lane & 15;
    int beg = rs[w], end = rs[w + 1];
    const float NEG = -__builtin_inff();
    f32x4 m0 = {NEG, NEG, NEG, NEG}, m1 = m0;
    for (int base = beg; base < end; base += 64) {
        int cnt = end - base;
        if (cnt > 64) cnt = 64;
        int sv = (lane < cnt) ? ssrc[base + lane] : 0;   // coalesced edge read
        int j = 0;
        for (; j + 7 < cnt; j += 8) {
            int sA = __shfl(sv, j + g);
            int sB = __shfl(sv, j + 4 + g);
            f32x4 vA = *(const f32x4*)(hin + (size_t)sA * DIM + sub * 4);
            f32x4 vB = *(const f32x4*)(hin + (size_t)sB * DIM + sub * 4);
            m0 = max4(m0, vA);
            m1 = max4(m1, vB);
        }
        for (; j + 3 < cnt; j += 4) {
            int sA = __shfl(sv, j + g);
            f32x4 vA = *(const f32x4*)(hin + (size_t)sA * DIM + sub * 4);
            m0 = max4(m0, vA);
        }
        if (j < cnt) {                        // wave-uniform branch
            int jg = j + g;
            if (jg >= cnt) jg = cnt - 1;      // clamp: re-max of a seen edge is a no-op
            int sA = __shfl(sv, jg);          // full-exec shfl, defined
            f32x4 vA = *(const f32x4*)(hin + (size_t)sA * DIM + sub * 4);
            m0 = max4(m0, vA);
        }
    }
    f32x4 m = max4(m0, m1);
#pragma unroll
    for (int c = 0; c < 4; ++c) {
        float v = m[c];
        v = fmaxf(v, __shfl_xor(v, 16));
        v = fmaxf(v, __shfl_xor(v, 32));
        m[c] = v;
    }
    if (g == 0) {
        if (end <= beg) m = (f32x4){0.f, 0.f, 0.f, 0.f};   // no in-edges -> 0
        *(f32x4*)(agg + (size_t)w * DIM + sub * 4) = m;
    }
}

// ---------------- fused GEMM: out = [agg|hin] @ B + bias (+relu), split-bf16 MFMA ----------------

__device__ __forceinline__ void cvt8(f32x4 a0, f32x4 a1, short8& hi, short8& lo) {
#pragma unroll
    for (int i = 0; i < 4; ++i) {
        short h0 = f2bf(a0[i]);
        hi[i] = h0;
        lo[i] = f2bf(a0[i] - bf2f(h0));
        short h1 = f2bf(a1[i]);
        hi[i + 4] = h1;
        lo[i + 4] = f2bf(a1[i] - bf2f(h1));
    }
}

__global__ void __launch_bounds__(256, 2) kgemm(
        const float* __restrict__ agg, const float* __restrict__ hin,
        const short* __restrict__ Bf, const float* __restrict__ bias,
        float* __restrict__ out, int N, int relu) {
    const int lane = threadIdx.x & 63;
    const int quad = lane >> 4;
    const int lrow = lane & 15;
    const int wv = (blockIdx.x * blockDim.x + threadIdx.x) >> 6;
    const int nwv = (gridDim.x * blockDim.x) >> 6;
    const int ntiles = (N + 15) >> 4;

    const short8* __restrict__ Bp = (const short8*)Bf;
    short8 bh[4][4], bl[4][4];
#pragma unroll
    for (int s = 0; s < 4; ++s)
#pragma unroll
        for (int t = 0; t < 4; ++t) {
            int blk = (s * 4 + t) * 2;
            bh[s][t] = Bp[blk * 64 + lane];
            bl[s][t] = Bp[blk * 64 + 64 + lane];
        }

    float bs[4];
#pragma unroll
    for (int t = 0; t < 4; ++t) bs[t] = bias[t * 16 + lrow];

    for (int tile = wv; tile < ntiles; tile += nwv) {
        const int m0 = tile << 4;
        int row = m0 + lrow;
        if (row >= N) row = N - 1;
        const float* pa = agg + (size_t)row * DIM + quad * 8;
        const float* ph = hin + (size_t)row * DIM + quad * 8;
        f32x4 a0 = *(const f32x4*)(pa);
        f32x4 a1 = *(const f32x4*)(pa + 4);
        f32x4 a2 = *(const f32x4*)(pa + 32);
        f32x4 a3 = *(const f32x4*)(pa + 36);
        f32x4 a4 = *(const f32x4*)(ph);
        f32x4 a5 = *(const f32x4*)(ph + 4);
        f32x4 a6 = *(const f32x4*)(ph + 32);
        f32x4 a7 = *(const f32x4*)(ph + 36);

        short8 ahi[4], alo[4];
        cvt8(a0, a1, ahi[0], alo[0]);
        cvt8(a2, a3, ahi[1], alo[1]);
        cvt8(a4, a5, ahi[2], alo[2]);
        cvt8(a6, a7, ahi[3], alo[3]);

        f32x4 acc[4] = {{0.f, 0.f, 0.f, 0.f}, {0.f, 0.f, 0.f, 0.f},
                        {0.f, 0.f, 0.f, 0.f}, {0.f, 0.f, 0.f, 0.f}};
#pragma unroll
        for (int s = 0; s < 4; ++s) {
#pragma unroll
            for (int t = 0; t < 4; ++t) {
                acc[t] = __builtin_amdgcn_mfma_f32_16x16x32_bf16(ahi[s], bh[s][t], acc[t], 0, 0, 0);
                acc[t] = __builtin_amdgcn_mfma_f32_16x16x32_bf16(alo[s], bh[s][t], acc[t], 0, 0, 0);
                acc[t] = __builtin_amdgcn_mfma_f32_16x16x32_bf16(ahi[s], bl[s][t], acc[t], 0, 0, 0);
            }
        }

#pragma unroll
        for (int t = 0; t < 4; ++t) {
            int col = t * 16 + lrow;
#pragma unroll
            for (int r = 0; r < 4; ++r) {
                int orow = m0 + quad * 4 + r;
                if (orow < N) {
                    float v = acc[t][r] + bs[t];
                    if (relu) v = fmaxf(v, 0.0f);
                    out[(size_t)orow * DIM + col] = v;
                }
            }
        }
    }
}

// ---------------- host ----------------

extern "C" void kernel_launch(void* const* d_in, const int* in_sizes, int n_in,
                              void* d_out, int out_size, void* d_ws, size_t ws_size,
                              hipStream_t stream) {
    const float* x  = (const float*)d_in[0];
    const int*   ei = (const int*)d_in[1];
    const float* Wl = (const float*)d_in[2];
    const float* bl = (const float*)d_in[3];
    const float* Wr = (const float*)d_in[4];
    int N = in_sizes[0] / DIM;
    int E = in_sizes[1] / 2;

    size_t nd = (size_t)N * DIM;
    float* hA   = (float*)d_ws;
    float* hB   = hA + nd;
    float* agg  = hB + nd;
    int*   rs   = (int*)(agg + nd);      // N+1 used, N+4 reserved
    int*   cur  = rs + (N + 4);
    int*   ssrc = cur + N;
    int*   bsum = ssrc + E;              // 2048 reserved
    short* Bf   = (short*)(bsum + 2048); // 6 layers * 16384 shorts
    int*   gbc  = (int*)(Bf + 6 * 16384);// 256 bucket cursors

    int NB = (N + 511) >> 9;             // <=256 for N<=131072
    int2* pairs = (int2*)hA;             // hA unused until layer 0

    hipMemsetAsync(cur, 0, (size_t)N * sizeof(int), stream);
    khist<<<(E + 255) / 256, 256, 0, stream>>>(ei, E, cur);
    int nb1 = (N + 511) / 512;
    kscan1<<<nb1, 512, 0, stream>>>(cur, N, rs, bsum);
    kscan2<<<1, 256, 0, stream>>>(bsum, nb1);
    kscan3<<<(N + 255) / 256, 256, 0, stream>>>(rs, cur, bsum, N, E);
    kbinit<<<1, 256, 0, stream>>>(rs, gbc, N, NB);
    kbin<<<(E + 4095) / 4096, 256, 0, stream>>>(ei, E, gbc, pairs, NB);
    kscat2<<<(E + 255) / 256, 256, 0, stream>>>(pairs, E, cur, ssrc);
    kprepw<<<(6 * 4 * 4 * 64 * 8 + 255) / 256, 256, 0, stream>>>(Wl, Wr, Bf);

    const float* hin = x;
    float* bufs[2] = {hA, hB};
    for (int l = 0; l < 6; ++l) {
        float* hout = (l == 5) ? (float*)d_out : bufs[l & 1];
        kagg<<<(N + 3) / 4, 256, 0, stream>>>(hin, rs, ssrc, agg, N);
        kgemm<<<512, 256, 0, stream>>>(agg, hin, Bf + l * 16384,
                                       bl + l * 64, hout, N, l < 5 ? 1 : 0);
        hin = hout;
    }
}

// Round 5
// 578.168 us; speedup vs baseline: 9.3978x; 1.1260x over previous
//
#include <hip/hip_runtime.h>
#include <hip/hip_bf16.h>
#include <math.h>

#define DIM 64

typedef __attribute__((ext_vector_type(8))) short short8;
typedef __attribute__((ext_vector_type(4))) float f32x4;

__device__ __forceinline__ short f2bf(float f) {
    unsigned u = __float_as_uint(f);
    unsigned r = (u + 0x7fffu + ((u >> 16) & 1u)) >> 16;   // RNE, no NaN inputs
    return (short)r;
}
__device__ __forceinline__ float bf2f(short s) {
    return __uint_as_float(((unsigned)(unsigned short)s) << 16);
}
__device__ __forceinline__ f32x4 max4(f32x4 a, f32x4 b) {
    f32x4 r;
#pragma unroll
    for (int i = 0; i < 4; ++i) r[i] = fmaxf(a[i], b[i]);
    return r;
}

// ---------------- CSR build (bucket-local, no global per-node histogram) ----------------
// bucket b = dst >> 9 (512 nodes per bucket, NB <= 256)

// per-bucket edge counts (LDS-aggregated)
__global__ void kbcnt(const int* __restrict__ ei, int E, int* __restrict__ gcnt) {
    __shared__ int h[256];
    int t = threadIdx.x;
    h[t] = 0;
    __syncthreads();
    for (int e = blockIdx.x * 256 + t; e < E; e += gridDim.x * 256)
        atomicAdd(&h[ei[E + e] >> 9], 1);
    __syncthreads();
    if (h[t]) atomicAdd(&gcnt[t], h[t]);
}

// single-block scan of bucket counts -> region starts gbs + kbin cursors gbc
__global__ void kbscan(const int* __restrict__ gcnt, int* __restrict__ gbs,
                       int* __restrict__ gbc, int NB, int E,
                       int* __restrict__ rs, int N) {
    __shared__ int sm[256];
    int t = threadIdx.x;
    int v = (t < NB) ? gcnt[t] : 0;
    sm[t] = v;
    __syncthreads();
    for (int off = 1; off < 256; off <<= 1) {
        int add = (t >= off) ? sm[t - off] : 0;
        __syncthreads();
        sm[t] += add;
        __syncthreads();
    }
    int excl = sm[t] - v;
    if (t < NB) { gbs[t] = excl; gbc[t] = excl; }
    if (t == NB - 1) gbs[NB] = excl + v;    // == E
    if (t == 0) rs[N] = E;
}

// Pass A: bin (src,dst) pairs by bucket into bucket-contiguous regions of `pairs`.
__global__ void kbin(const int* __restrict__ ei, int E,
                     int* __restrict__ gbc, int2* __restrict__ pairs, int NB) {
    __shared__ int hist[256];
    __shared__ int basep[256];
    const int t = threadIdx.x;
    const int c0 = blockIdx.x * 4096;
    hist[t] = 0;
    __syncthreads();
    int s[16], d[16];
#pragma unroll
    for (int i = 0; i < 16; ++i) {
        int e = c0 + i * 256 + t;
        if (e < E) {
            s[i] = ei[e];
            d[i] = ei[E + e];
            atomicAdd(&hist[d[i] >> 9], 1);
        } else d[i] = -1;
    }
    __syncthreads();
    if (t < NB) {
        basep[t] = atomicAdd(&gbc[t], hist[t]);
        hist[t] = 0;
    }
    __syncthreads();
#pragma unroll
    for (int i = 0; i < 16; ++i) {
        if (d[i] >= 0) {
            int b = d[i] >> 9;
            int off = atomicAdd(&hist[b], 1);
            int2 pr; pr.x = s[i]; pr.y = d[i];
            pairs[basep[b] + off] = pr;
        }
    }
}

// Pass B: one block per bucket — LDS per-node hist + scan + bucket-local scatter.
__global__ void __launch_bounds__(256) kfinal(
        const int2* __restrict__ pairs, const int* __restrict__ gbs,
        int* __restrict__ rs, int* __restrict__ ssrc, int N) {
    __shared__ int lcnt[512];
    __shared__ int lcur[512];
    __shared__ int ps[256];
    const int b = blockIdx.x;
    const int t = threadIdx.x;
    const int n0 = b << 9;
    const int e0 = gbs[b], e1 = gbs[b + 1];
    lcnt[t] = 0;
    lcnt[t + 256] = 0;
    __syncthreads();
    for (int e = e0 + t; e < e1; e += 256)
        atomicAdd(&lcnt[pairs[e].y - n0], 1);
    __syncthreads();
    // exclusive scan of 512 counters (2 per thread)
    int c0 = lcnt[2 * t], c1 = lcnt[2 * t + 1];
    int sum = c0 + c1;
    ps[t] = sum;
    __syncthreads();
    for (int off = 1; off < 256; off <<= 1) {
        int add = (t >= off) ? ps[t - off] : 0;
        __syncthreads();
        ps[t] += add;
        __syncthreads();
    }
    int excl = ps[t] - sum;
    lcur[2 * t] = excl;
    lcur[2 * t + 1] = excl + c0;
    int n = n0 + 2 * t;
    if (n < N) rs[n] = e0 + excl;
    if (n + 1 < N) rs[n + 1] = e0 + excl + c0;
    __syncthreads();
    for (int e = e0 + t; e < e1; e += 256) {
        int2 pr = pairs[e];
        int p = atomicAdd(&lcur[pr.y - n0], 1);
        ssrc[e0 + p] = pr.x;          // write stays inside this bucket's 32KB region
    }
}

// ---------------- weight prep: B[k][j] -> MFMA B-fragment order, bf16 hi/lo ----------------

__global__ void kprepw(const float* __restrict__ Wl, const float* __restrict__ Wr,
                       short* __restrict__ Bf) {
    int id = blockIdx.x * blockDim.x + threadIdx.x;
    if (id >= 6 * 4 * 4 * 64 * 8) return;
    int i = id & 7;
    int lane = (id >> 3) & 63;
    int t = (id >> 9) & 3;
    int s = (id >> 11) & 3;
    int layer = id >> 13;
    int k = s * 32 + (lane >> 4) * 8 + i;
    int j = t * 16 + (lane & 15);
    float v = (k < 64) ? Wl[(layer * 64 + j) * 64 + k]
                       : Wr[(layer * 64 + j) * 64 + (k - 64)];
    short hi = f2bf(v);
    short lo = f2bf(v - bf2f(hi));
    int blk = ((layer * 4 + s) * 4 + t) * 2;
    int base = blk * 512 + lane * 8 + i;
    Bf[base] = hi;          // hl = 0
    Bf[base + 512] = lo;    // hl = 1
}

// ---------------- aggregation: one wave per node, 4 rows in flight per load ----------------
// NOTE: every __shfl executes with FULL exec (wave-uniform branches only).

__global__ void kagg(const float* __restrict__ hin, const int* __restrict__ rs,
                     const int* __restrict__ ssrc, float* __restrict__ agg, int N) {
    int w = (blockIdx.x * blockDim.x + threadIdx.x) >> 6;
    int lane = threadIdx.x & 63;
    if (w >= N) return;
    int g = lane >> 4, sub = lane & 15;
    int beg = rs[w], end = rs[w + 1];
    const float NEG = -__builtin_inff();
    f32x4 m0 = {NEG, NEG, NEG, NEG}, m1 = m0;
    for (int base = beg; base < end; base += 64) {
        int cnt = end - base;
        if (cnt > 64) cnt = 64;
        int sv = (lane < cnt) ? ssrc[base + lane] : 0;   // coalesced edge read
        int j = 0;
        for (; j + 7 < cnt; j += 8) {
            int sA = __shfl(sv, j + g);
            int sB = __shfl(sv, j + 4 + g);
            f32x4 vA = *(const f32x4*)(hin + (size_t)sA * DIM + sub * 4);
            f32x4 vB = *(const f32x4*)(hin + (size_t)sB * DIM + sub * 4);
            m0 = max4(m0, vA);
            m1 = max4(m1, vB);
        }
        for (; j + 3 < cnt; j += 4) {
            int sA = __shfl(sv, j + g);
            f32x4 vA = *(const f32x4*)(hin + (size_t)sA * DIM + sub * 4);
            m0 = max4(m0, vA);
        }
        if (j < cnt) {                        // wave-uniform branch
            int jg = j + g;
            if (jg >= cnt) jg = cnt - 1;      // clamp: re-max of a seen edge is a no-op
            int sA = __shfl(sv, jg);
            f32x4 vA = *(const f32x4*)(hin + (size_t)sA * DIM + sub * 4);
            m0 = max4(m0, vA);
        }
    }
    f32x4 m = max4(m0, m1);
#pragma unroll
    for (int c = 0; c < 4; ++c) {
        float v = m[c];
        v = fmaxf(v, __shfl_xor(v, 16));
        v = fmaxf(v, __shfl_xor(v, 32));
        m[c] = v;
    }
    if (g == 0) {
        if (end <= beg) m = (f32x4){0.f, 0.f, 0.f, 0.f};   // no in-edges -> 0
        *(f32x4*)(agg + (size_t)w * DIM + sub * 4) = m;
    }
}

// ---------------- fused GEMM: out = [agg|hin] @ B + bias (+relu), split-bf16 MFMA ----------------

__device__ __forceinline__ void cvt8(f32x4 a0, f32x4 a1, short8& hi, short8& lo) {
#pragma unroll
    for (int i = 0; i < 4; ++i) {
        short h0 = f2bf(a0[i]);
        hi[i] = h0;
        lo[i] = f2bf(a0[i] - bf2f(h0));
        short h1 = f2bf(a1[i]);
        hi[i + 4] = h1;
        lo[i + 4] = f2bf(a1[i] - bf2f(h1));
    }
}

__global__ void __launch_bounds__(256, 2) kgemm(
        const float* __restrict__ agg, const float* __restrict__ hin,
        const short* __restrict__ Bf, const float* __restrict__ bias,
        float* __restrict__ out, int N, int relu) {
    const int lane = threadIdx.x & 63;
    const int quad = lane >> 4;
    const int lrow = lane & 15;
    const int wv = (blockIdx.x * blockDim.x + threadIdx.x) >> 6;
    const int nwv = (gridDim.x * blockDim.x) >> 6;
    const int ntiles = (N + 15) >> 4;

    const short8* __restrict__ Bp = (const short8*)Bf;
    short8 bh[4][4], bl[4][4];
#pragma unroll
    for (int s = 0; s < 4; ++s)
#pragma unroll
        for (int t = 0; t < 4; ++t) {
            int blk = (s * 4 + t) * 2;
            bh[s][t] = Bp[blk * 64 + lane];
            bl[s][t] = Bp[blk * 64 + 64 + lane];
        }

    float bs[4];
#pragma unroll
    for (int t = 0; t < 4; ++t) bs[t] = bias[t * 16 + lrow];

    for (int tile = wv; tile < ntiles; tile += nwv) {
        const int m0 = tile << 4;
        int row = m0 + lrow;
        if (row >= N) row = N - 1;
        const float* pa = agg + (size_t)row * DIM + quad * 8;
        const float* ph = hin + (size_t)row * DIM + quad * 8;
        f32x4 a0 = *(const f32x4*)(pa);
        f32x4 a1 = *(const f32x4*)(pa + 4);
        f32x4 a2 = *(const f32x4*)(pa + 32);
        f32x4 a3 = *(const f32x4*)(pa + 36);
        f32x4 a4 = *(const f32x4*)(ph);
        f32x4 a5 = *(const f32x4*)(ph + 4);
        f32x4 a6 = *(const f32x4*)(ph + 32);
        f32x4 a7 = *(const f32x4*)(ph + 36);

        short8 ahi[4], alo[4];
        cvt8(a0, a1, ahi[0], alo[0]);
        cvt8(a2, a3, ahi[1], alo[1]);
        cvt8(a4, a5, ahi[2], alo[2]);
        cvt8(a6, a7, ahi[3], alo[3]);

        f32x4 acc[4] = {{0.f, 0.f, 0.f, 0.f}, {0.f, 0.f, 0.f, 0.f},
                        {0.f, 0.f, 0.f, 0.f}, {0.f, 0.f, 0.f, 0.f}};
#pragma unroll
        for (int s = 0; s < 4; ++s) {
#pragma unroll
            for (int t = 0; t < 4; ++t) {
                acc[t] = __builtin_amdgcn_mfma_f32_16x16x32_bf16(ahi[s], bh[s][t], acc[t], 0, 0, 0);
                acc[t] = __builtin_amdgcn_mfma_f32_16x16x32_bf16(alo[s], bh[s][t], acc[t], 0, 0, 0);
                acc[t] = __builtin_amdgcn_mfma_f32_16x16x32_bf16(ahi[s], bl[s][t], acc[t], 0, 0, 0);
            }
        }

#pragma unroll
        for (int t = 0; t < 4; ++t) {
            int col = t * 16 + lrow;
#pragma unroll
            for (int r = 0; r < 4; ++r) {
                int orow = m0 + quad * 4 + r;
                if (orow < N) {
                    float v = acc[t][r] + bs[t];
                    if (relu) v = fmaxf(v, 0.0f);
                    out[(size_t)orow * DIM + col] = v;
                }
            }
        }
    }
}

// ---------------- host ----------------

extern "C" void kernel_launch(void* const* d_in, const int* in_sizes, int n_in,
                              void* d_out, int out_size, void* d_ws, size_t ws_size,
                              hipStream_t stream) {
    const float* x  = (const float*)d_in[0];
    const int*   ei = (const int*)d_in[1];
    const float* Wl = (const float*)d_in[2];
    const float* bl = (const float*)d_in[3];
    const float* Wr = (const float*)d_in[4];
    int N = in_sizes[0] / DIM;
    int E = in_sizes[1] / 2;

    size_t nd = (size_t)N * DIM;
    float* hA   = (float*)d_ws;
    float* hB   = hA + nd;
    float* agg  = hB + nd;
    int*   rs   = (int*)(agg + nd);      // N+1 used, N+4 reserved
    int*   ssrc = rs + (N + 4);
    int*   gcnt = ssrc + E;              // 256
    int*   gbs  = gcnt + 256;            // NB+1 (260 reserved)
    int*   gbc  = gbs + 260;             // 256
    short* Bf   = (short*)(gbc + 256);   // 6 layers * 16384 shorts

    int NB = (N + 511) >> 9;             // 196 for N=100000
    int2* pairs = (int2*)hA;             // hA unused until layer 0

    hipMemsetAsync(gcnt, 0, 256 * sizeof(int), stream);
    kbcnt<<<640, 256, 0, stream>>>(ei, E, gcnt);
    kbscan<<<1, 256, 0, stream>>>(gcnt, gbs, gbc, NB, E, rs, N);
    kbin<<<(E + 4095) / 4096, 256, 0, stream>>>(ei, E, gbc, pairs, NB);
    kfinal<<<NB, 256, 0, stream>>>(pairs, gbs, rs, ssrc, N);
    kprepw<<<(6 * 4 * 4 * 64 * 8 + 255) / 256, 256, 0, stream>>>(Wl, Wr, Bf);

    const float* hin = x;
    float* bufs[2] = {hA, hB};
    for (int l = 0; l < 6; ++l) {
        float* hout = (l == 5) ? (float*)d_out : bufs[l & 1];
        kagg<<<(N + 3) / 4, 256, 0, stream>>>(hin, rs, ssrc, agg, N);
        kgemm<<<512, 256, 0, stream>>>(agg, hin, Bf + l * 16384,
                                       bl + l * 64, hout, N, l < 5 ? 1 : 0);
        hin = hout;
    }
}

// Round 6
// 513.512 us; speedup vs baseline: 10.5810x; 1.1259x over previous
//
#include <hip/hip_runtime.h>
#include <hip/hip_bf16.h>
#include <math.h>

#define DIM 64

typedef __attribute__((ext_vector_type(8))) short short8;
typedef __attribute__((ext_vector_type(4))) float f32x4;
typedef _Float16 half_t;
typedef __attribute__((ext_vector_type(4))) _Float16 h16x4;
typedef __attribute__((ext_vector_type(8))) _Float16 h16x8;

__device__ __forceinline__ short f2bf(float f) {
    unsigned u = __float_as_uint(f);
    unsigned r = (u + 0x7fffu + ((u >> 16) & 1u)) >> 16;   // RNE, no NaN inputs
    return (short)r;
}
__device__ __forceinline__ float bf2f(short s) {
    return __uint_as_float(((unsigned)(unsigned short)s) << 16);
}
__device__ __forceinline__ h16x4 hmax4(h16x4 a, h16x4 b) {
    h16x4 r;
#pragma unroll
    for (int i = 0; i < 4; ++i) r[i] = (a[i] > b[i]) ? a[i] : b[i];
    return r;
}

// ---------------- CSR build (bucket-local; pairs packed src<<9 | dst&511) ----------------

__global__ void kbcnt(const int* __restrict__ ei, int E, int* __restrict__ gcnt) {
    __shared__ int h[256];
    int t = threadIdx.x;
    h[t] = 0;
    __syncthreads();
    for (int e = blockIdx.x * 256 + t; e < E; e += gridDim.x * 256)
        atomicAdd(&h[ei[E + e] >> 9], 1);
    __syncthreads();
    if (h[t]) atomicAdd(&gcnt[t], h[t]);
}

__global__ void kbscan(const int* __restrict__ gcnt, int* __restrict__ gbs,
                       int* __restrict__ gbc, int NB, int E,
                       int* __restrict__ rs, int N) {
    __shared__ int sm[256];
    int t = threadIdx.x;
    int v = (t < NB) ? gcnt[t] : 0;
    sm[t] = v;
    __syncthreads();
    for (int off = 1; off < 256; off <<= 1) {
        int add = (t >= off) ? sm[t - off] : 0;
        __syncthreads();
        sm[t] += add;
        __syncthreads();
    }
    int excl = sm[t] - v;
    if (t < NB) { gbs[t] = excl; gbc[t] = excl; }
    if (t == NB - 1) gbs[NB] = excl + v;    // == E
    if (t == 0) rs[N] = E;
}

__global__ void kbin(const int* __restrict__ ei, int E,
                     int* __restrict__ gbc, int* __restrict__ pairs, int NB) {
    __shared__ int hist[256];
    __shared__ int basep[256];
    const int t = threadIdx.x;
    const int c0 = blockIdx.x * 4096;
    hist[t] = 0;
    __syncthreads();
    int s[16], d[16];
#pragma unroll
    for (int i = 0; i < 16; ++i) {
        int e = c0 + i * 256 + t;
        if (e < E) {
            s[i] = ei[e];
            d[i] = ei[E + e];
            atomicAdd(&hist[d[i] >> 9], 1);
        } else d[i] = -1;
    }
    __syncthreads();
    if (t < NB) {
        basep[t] = atomicAdd(&gbc[t], hist[t]);
        hist[t] = 0;
    }
    __syncthreads();
#pragma unroll
    for (int i = 0; i < 16; ++i) {
        if (d[i] >= 0) {
            int b = d[i] >> 9;
            int off = atomicAdd(&hist[b], 1);
            pairs[basep[b] + off] = (s[i] << 9) | (d[i] & 511);
        }
    }
}

__global__ void __launch_bounds__(256) kfinal(
        const int* __restrict__ pairs, const int* __restrict__ gbs,
        int* __restrict__ rs, int* __restrict__ ssrc, int N) {
    __shared__ int lcnt[512];
    __shared__ int lcur[512];
    __shared__ int ps[256];
    const int b = blockIdx.x;
    const int t = threadIdx.x;
    const int n0 = b << 9;
    const int e0 = gbs[b], e1 = gbs[b + 1];
    lcnt[t] = 0;
    lcnt[t + 256] = 0;
    __syncthreads();
    for (int e = e0 + t; e < e1; e += 256)
        atomicAdd(&lcnt[pairs[e] & 511], 1);
    __syncthreads();
    int c0 = lcnt[2 * t], c1 = lcnt[2 * t + 1];
    int sum = c0 + c1;
    ps[t] = sum;
    __syncthreads();
    for (int off = 1; off < 256; off <<= 1) {
        int add = (t >= off) ? ps[t - off] : 0;
        __syncthreads();
        ps[t] += add;
        __syncthreads();
    }
    int excl = ps[t] - sum;
    lcur[2 * t] = excl;
    lcur[2 * t + 1] = excl + c0;
    int n = n0 + 2 * t;
    if (n < N) rs[n] = e0 + excl;
    if (n + 1 < N) rs[n + 1] = e0 + excl + c0;
    __syncthreads();
    for (int e = e0 + t; e < e1; e += 256) {
        int p = pairs[e];
        int pos = atomicAdd(&lcur[p & 511], 1);
        ssrc[e0 + pos] = (int)((unsigned)p >> 9);
    }
}

// ---------------- fp32 -> fp16 shadow ----------------

__global__ void kcvt(const float* __restrict__ x, half_t* __restrict__ h16, int n4) {
    int i = blockIdx.x * blockDim.x + threadIdx.x;
    if (i < n4) {
        f32x4 v = ((const f32x4*)x)[i];
        h16x4 r;
#pragma unroll
        for (int c = 0; c < 4; ++c) r[c] = (half_t)v[c];
        ((h16x4*)h16)[i] = r;
    }
}

// ---------------- weight prep: B[k][j] -> MFMA B-fragment order, bf16 hi/lo ----------------

__global__ void kprepw(const float* __restrict__ Wl, const float* __restrict__ Wr,
                       short* __restrict__ Bf) {
    int id = blockIdx.x * blockDim.x + threadIdx.x;
    if (id >= 6 * 4 * 4 * 64 * 8) return;
    int i = id & 7;
    int lane = (id >> 3) & 63;
    int t = (id >> 9) & 3;
    int s = (id >> 11) & 3;
    int layer = id >> 13;
    int k = s * 32 + (lane >> 4) * 8 + i;
    int j = t * 16 + (lane & 15);
    float v = (k < 64) ? Wl[(layer * 64 + j) * 64 + k]
                       : Wr[(layer * 64 + j) * 64 + (k - 64)];
    short hi = f2bf(v);
    short lo = f2bf(v - bf2f(hi));
    int blk = ((layer * 4 + s) * 4 + t) * 2;
    int base = blk * 512 + lane * 8 + i;
    Bf[base] = hi;          // hl = 0
    Bf[base + 512] = lo;    // hl = 1
}

// ---------------- aggregation: fp16 gather, one wave per node, 16 edges in flight ----------------
// NOTE: every __shfl executes with FULL exec (wave-uniform branches only).

__global__ void kagg(const half_t* __restrict__ h16, const int* __restrict__ rs,
                     const int* __restrict__ ssrc, half_t* __restrict__ agg16, int N) {
    int w = (blockIdx.x * blockDim.x + threadIdx.x) >> 6;
    int lane = threadIdx.x & 63;
    if (w >= N) return;
    int g = lane >> 4, sub = lane & 15;
    int beg = rs[w], end = rs[w + 1];
    const half_t NEG = (half_t)(-65504.0f);   // lowest finite fp16; real values always >= this
    h16x4 m0 = {NEG, NEG, NEG, NEG}, m1 = m0, m2 = m0, m3 = m0;
    for (int base = beg; base < end; base += 64) {
        int cnt = end - base;
        if (cnt > 64) cnt = 64;
        int sv = (lane < cnt) ? ssrc[base + lane] : 0;   // coalesced edge read
        int j = 0;
        for (; j + 15 < cnt; j += 16) {
            int s0 = __shfl(sv, j + g);
            int s1 = __shfl(sv, j + 4 + g);
            int s2 = __shfl(sv, j + 8 + g);
            int s3 = __shfl(sv, j + 12 + g);
            h16x4 v0 = *(const h16x4*)(h16 + (size_t)s0 * DIM + sub * 4);
            h16x4 v1 = *(const h16x4*)(h16 + (size_t)s1 * DIM + sub * 4);
            h16x4 v2 = *(const h16x4*)(h16 + (size_t)s2 * DIM + sub * 4);
            h16x4 v3 = *(const h16x4*)(h16 + (size_t)s3 * DIM + sub * 4);
            m0 = hmax4(m0, v0); m1 = hmax4(m1, v1);
            m2 = hmax4(m2, v2); m3 = hmax4(m3, v3);
        }
        for (; j + 3 < cnt; j += 4) {
            int s0 = __shfl(sv, j + g);
            h16x4 v0 = *(const h16x4*)(h16 + (size_t)s0 * DIM + sub * 4);
            m0 = hmax4(m0, v0);
        }
        if (j < cnt) {                        // wave-uniform branch
            int jg = j + g;
            if (jg >= cnt) jg = cnt - 1;      // clamp: re-max of a seen edge is a no-op
            int s0 = __shfl(sv, jg);
            h16x4 v0 = *(const h16x4*)(h16 + (size_t)s0 * DIM + sub * 4);
            m0 = hmax4(m0, v0);
        }
    }
    h16x4 mm = hmax4(hmax4(m0, m1), hmax4(m2, m3));
    f32x4 mf;
#pragma unroll
    for (int c = 0; c < 4; ++c) {
        float v = (float)mm[c];
        v = fmaxf(v, __shfl_xor(v, 16));
        v = fmaxf(v, __shfl_xor(v, 32));
        mf[c] = v;
    }
    if (g == 0) {
        h16x4 r;
        if (end <= beg) {
            r = (h16x4){(half_t)0.f, (half_t)0.f, (half_t)0.f, (half_t)0.f};
        } else {
#pragma unroll
            for (int c = 0; c < 4; ++c) r[c] = (half_t)mf[c];   // exact (max of fp16s)
        }
        *(h16x4*)(agg16 + (size_t)w * DIM + sub * 4) = r;
    }
}

// ---------------- fused GEMM: out = [agg|hin] @ B + bias (+relu), split-bf16 MFMA ----------------

__device__ __forceinline__ void cvt8(f32x4 a0, f32x4 a1, short8& hi, short8& lo) {
#pragma unroll
    for (int i = 0; i < 4; ++i) {
        short h0 = f2bf(a0[i]);
        hi[i] = h0;
        lo[i] = f2bf(a0[i] - bf2f(h0));
        short h1 = f2bf(a1[i]);
        hi[i + 4] = h1;
        lo[i + 4] = f2bf(a1[i] - bf2f(h1));
    }
}
__device__ __forceinline__ void cvt8h(h16x8 a, short8& hi, short8& lo) {
#pragma unroll
    for (int i = 0; i < 8; ++i) {
        float f = (float)a[i];
        short h0 = f2bf(f);
        hi[i] = h0;
        lo[i] = f2bf(f - bf2f(h0));
    }
}

__global__ void __launch_bounds__(256, 2) kgemm(
        const half_t* __restrict__ agg16, const float* __restrict__ hin,
        const short* __restrict__ Bf, const float* __restrict__ bias,
        float* __restrict__ out, half_t* __restrict__ h16out,
        int N, int relu, int wh16) {
    const int lane = threadIdx.x & 63;
    const int quad = lane >> 4;
    const int lrow = lane & 15;
    const int wv = (blockIdx.x * blockDim.x + threadIdx.x) >> 6;
    const int nwv = (gridDim.x * blockDim.x) >> 6;
    const int ntiles = (N + 15) >> 4;

    const short8* __restrict__ Bp = (const short8*)Bf;
    short8 bh[4][4], bl[4][4];
#pragma unroll
    for (int s = 0; s < 4; ++s)
#pragma unroll
        for (int t = 0; t < 4; ++t) {
            int blk = (s * 4 + t) * 2;
            bh[s][t] = Bp[blk * 64 + lane];
            bl[s][t] = Bp[blk * 64 + 64 + lane];
        }

    float bs[4];
#pragma unroll
    for (int t = 0; t < 4; ++t) bs[t] = bias[t * 16 + lrow];

    for (int tile = wv; tile < ntiles; tile += nwv) {
        const int m0 = tile << 4;
        int row = m0 + lrow;
        if (row >= N) row = N - 1;
        const half_t* pa = agg16 + (size_t)row * DIM + quad * 8;
        const float*  ph = hin   + (size_t)row * DIM + quad * 8;
        h16x8 aa0 = *(const h16x8*)(pa);
        h16x8 aa1 = *(const h16x8*)(pa + 32);
        f32x4 a4 = *(const f32x4*)(ph);
        f32x4 a5 = *(const f32x4*)(ph + 4);
        f32x4 a6 = *(const f32x4*)(ph + 32);
        f32x4 a7 = *(const f32x4*)(ph + 36);

        short8 ahi[4], alo[4];
        cvt8h(aa0, ahi[0], alo[0]);
        cvt8h(aa1, ahi[1], alo[1]);
        cvt8(a4, a5, ahi[2], alo[2]);
        cvt8(a6, a7, ahi[3], alo[3]);

        f32x4 acc[4] = {{0.f, 0.f, 0.f, 0.f}, {0.f, 0.f, 0.f, 0.f},
                        {0.f, 0.f, 0.f, 0.f}, {0.f, 0.f, 0.f, 0.f}};
#pragma unroll
        for (int s = 0; s < 4; ++s) {
#pragma unroll
            for (int t = 0; t < 4; ++t) {
                acc[t] = __builtin_amdgcn_mfma_f32_16x16x32_bf16(ahi[s], bh[s][t], acc[t], 0, 0, 0);
                acc[t] = __builtin_amdgcn_mfma_f32_16x16x32_bf16(alo[s], bh[s][t], acc[t], 0, 0, 0);
                acc[t] = __builtin_amdgcn_mfma_f32_16x16x32_bf16(ahi[s], bl[s][t], acc[t], 0, 0, 0);
            }
        }

#pragma unroll
        for (int t = 0; t < 4; ++t) {
            int col = t * 16 + lrow;
#pragma unroll
            for (int r = 0; r < 4; ++r) {
                int orow = m0 + quad * 4 + r;
                if (orow < N) {
                    float v = acc[t][r] + bs[t];
                    if (relu) v = fmaxf(v, 0.0f);
                    out[(size_t)orow * DIM + col] = v;
                    if (wh16) h16out[(size_t)orow * DIM + col] = (half_t)v;
                }
            }
        }
    }
}

// ---------------- host ----------------

extern "C" void kernel_launch(void* const* d_in, const int* in_sizes, int n_in,
                              void* d_out, int out_size, void* d_ws, size_t ws_size,
                              hipStream_t stream) {
    const float* x  = (const float*)d_in[0];
    const int*   ei = (const int*)d_in[1];
    const float* Wl = (const float*)d_in[2];
    const float* bl = (const float*)d_in[3];
    const float* Wr = (const float*)d_in[4];
    int N = in_sizes[0] / DIM;
    int E = in_sizes[1] / 2;

    size_t nd = (size_t)N * DIM;
    float*  hA    = (float*)d_ws;
    float*  hB    = hA + nd;
    half_t* h16   = (half_t*)(hB + nd);      // nd halfs (12.8 MB)
    half_t* agg16 = h16 + nd;                // nd halfs
    int*    rs    = (int*)(agg16 + nd);      // N+1 used, N+4 reserved
    int*    ssrc  = rs + (N + 4);
    int*    gcnt  = ssrc + E;                // 256
    int*    gbs   = gcnt + 256;              // NB+1 (260 reserved)
    int*    gbc   = gbs + 260;               // 256
    short*  Bf    = (short*)(gbc + 256);     // 6 layers * 16384 shorts

    int NB = (N + 511) >> 9;                 // 196 for N=100000
    int* pairs = (int*)hA;                   // hA unused until layer 0

    hipMemsetAsync(gcnt, 0, 256 * sizeof(int), stream);
    kbcnt<<<640, 256, 0, stream>>>(ei, E, gcnt);
    kbscan<<<1, 256, 0, stream>>>(gcnt, gbs, gbc, NB, E, rs, N);
    kbin<<<(E + 4095) / 4096, 256, 0, stream>>>(ei, E, gbc, pairs, NB);
    kfinal<<<NB, 256, 0, stream>>>(pairs, gbs, rs, ssrc, N);
    kprepw<<<(6 * 4 * 4 * 64 * 8 + 255) / 256, 256, 0, stream>>>(Wl, Wr, Bf);
    kcvt<<<((int)(nd / 4) + 255) / 256, 256, 0, stream>>>(x, h16, (int)(nd / 4));

    const float* hin = x;
    float* bufs[2] = {hA, hB};
    for (int l = 0; l < 6; ++l) {
        float* hout = (l == 5) ? (float*)d_out : bufs[l & 1];
        kagg<<<(N + 3) / 4, 256, 0, stream>>>(h16, rs, ssrc, agg16, N);
        kgemm<<<512, 256, 0, stream>>>(agg16, hin, Bf + l * 16384, bl + l * 64,
                                       hout, h16, N, l < 5 ? 1 : 0, l < 5 ? 1 : 0);
        hin = hout;
    }
}

// Round 7
// 503.758 us; speedup vs baseline: 10.7859x; 1.0194x over previous
//
#include <hip/hip_runtime.h>
#include <hip/hip_bf16.h>
#include <math.h>

#define DIM 64

typedef _Float16 half_t;
typedef __attribute__((ext_vector_type(8))) _Float16 half8;
typedef __attribute__((ext_vector_type(4))) _Float16 h16x4;
typedef __attribute__((ext_vector_type(4))) float f32x4;

__device__ __forceinline__ half8 hmax8(half8 a, half8 b) {
    half8 r;
#pragma unroll
    for (int i = 0; i < 8; ++i) r[i] = (a[i] > b[i]) ? a[i] : b[i];
    return r;
}
__device__ __forceinline__ half8 shfl_xor_h8(half8 v, int mask) {
    union { half8 h; int i[4]; } u;
    u.h = v;
#pragma unroll
    for (int k = 0; k < 4; ++k) u.i[k] = __shfl_xor(u.i[k], mask);
    return u.h;
}

// ---------------- CSR build (bucket-local; pairs packed src<<9 | dst&511) ----------------

__global__ void kbcnt(const int* __restrict__ ei, int E, int* __restrict__ gcnt) {
    __shared__ int h[256];
    int t = threadIdx.x;
    h[t] = 0;
    __syncthreads();
    for (int e = blockIdx.x * 256 + t; e < E; e += gridDim.x * 256)
        atomicAdd(&h[ei[E + e] >> 9], 1);
    __syncthreads();
    if (h[t]) atomicAdd(&gcnt[t], h[t]);
}

__global__ void kbscan(const int* __restrict__ gcnt, int* __restrict__ gbs,
                       int* __restrict__ gbc, int NB, int E,
                       int* __restrict__ rs, int N) {
    __shared__ int sm[256];
    int t = threadIdx.x;
    int v = (t < NB) ? gcnt[t] : 0;
    sm[t] = v;
    __syncthreads();
    for (int off = 1; off < 256; off <<= 1) {
        int add = (t >= off) ? sm[t - off] : 0;
        __syncthreads();
        sm[t] += add;
        __syncthreads();
    }
    int excl = sm[t] - v;
    if (t < NB) { gbs[t] = excl; gbc[t] = excl; }
    if (t == NB - 1) gbs[NB] = excl + v;    // == E
    if (t == 0) rs[N] = E;
}

__global__ void kbin(const int* __restrict__ ei, int E,
                     int* __restrict__ gbc, int* __restrict__ pairs, int NB) {
    __shared__ int hist[256];
    __shared__ int basep[256];
    const int t = threadIdx.x;
    const int c0 = blockIdx.x * 4096;
    hist[t] = 0;
    __syncthreads();
    int s[16], d[16];
#pragma unroll
    for (int i = 0; i < 16; ++i) {
        int e = c0 + i * 256 + t;
        if (e < E) {
            s[i] = ei[e];
            d[i] = ei[E + e];
            atomicAdd(&hist[d[i] >> 9], 1);
        } else d[i] = -1;
    }
    __syncthreads();
    if (t < NB) {
        basep[t] = atomicAdd(&gbc[t], hist[t]);
        hist[t] = 0;
    }
    __syncthreads();
#pragma unroll
    for (int i = 0; i < 16; ++i) {
        if (d[i] >= 0) {
            int b = d[i] >> 9;
            int off = atomicAdd(&hist[b], 1);
            pairs[basep[b] + off] = (s[i] << 9) | (d[i] & 511);
        }
    }
}

// ssrc stores BYTE offsets (src * 128) for the fp16 row gather.
__global__ void __launch_bounds__(256) kfinal(
        const int* __restrict__ pairs, const int* __restrict__ gbs,
        int* __restrict__ rs, int* __restrict__ ssrc, int N) {
    __shared__ int lcnt[512];
    __shared__ int lcur[512];
    __shared__ int ps[256];
    const int b = blockIdx.x;
    const int t = threadIdx.x;
    const int n0 = b << 9;
    const int e0 = gbs[b], e1 = gbs[b + 1];
    lcnt[t] = 0;
    lcnt[t + 256] = 0;
    __syncthreads();
    for (int e = e0 + t; e < e1; e += 256)
        atomicAdd(&lcnt[pairs[e] & 511], 1);
    __syncthreads();
    int c0 = lcnt[2 * t], c1 = lcnt[2 * t + 1];
    int sum = c0 + c1;
    ps[t] = sum;
    __syncthreads();
    for (int off = 1; off < 256; off <<= 1) {
        int add = (t >= off) ? ps[t - off] : 0;
        __syncthreads();
        ps[t] += add;
        __syncthreads();
    }
    int excl = ps[t] - sum;
    lcur[2 * t] = excl;
    lcur[2 * t + 1] = excl + c0;
    int n = n0 + 2 * t;
    if (n < N) rs[n] = e0 + excl;
    if (n + 1 < N) rs[n + 1] = e0 + excl + c0;
    __syncthreads();
    for (int e = e0 + t; e < e1; e += 256) {
        int p = pairs[e];
        int pos = atomicAdd(&lcur[p & 511], 1);
        ssrc[e0 + pos] = (int)((unsigned)p >> 9) << 7;   // byte offset of fp16 row
    }
}

// ---------------- fp32 x -> fp16 hi/lo planes ----------------

__global__ void kcvt(const float* __restrict__ x, half_t* __restrict__ phi,
                     half_t* __restrict__ plo, int n4) {
    int i = blockIdx.x * blockDim.x + threadIdx.x;
    if (i < n4) {
        f32x4 v = ((const f32x4*)x)[i];
        h16x4 hi, lo;
#pragma unroll
        for (int c = 0; c < 4; ++c) {
            hi[c] = (half_t)v[c];
            lo[c] = (half_t)(v[c] - (float)hi[c]);
        }
        ((h16x4*)phi)[i] = hi;
        ((h16x4*)plo)[i] = lo;
    }
}

// ---------------- weight prep: fp16 hi/lo MFMA B-fragments ----------------
// B[k][j], k in [0,128): k<64 -> Wl[j][k]; k>=64 -> Wr[j][k-64]
// frag f = (s*4+t)*2 (+1 for lo); element [lane][i]: k = s*32+(lane>>4)*8+i, j = t*16+(lane&15)

__global__ void kprepw(const float* __restrict__ Wl, const float* __restrict__ Wr,
                       half_t* __restrict__ Bf) {
    int id = blockIdx.x * blockDim.x + threadIdx.x;
    if (id >= 6 * 4 * 4 * 64 * 8) return;
    int i = id & 7;
    int lane = (id >> 3) & 63;
    int t = (id >> 9) & 3;
    int s = (id >> 11) & 3;
    int layer = id >> 13;
    int k = s * 32 + (lane >> 4) * 8 + i;
    int j = t * 16 + (lane & 15);
    float v = (k < 64) ? Wl[(layer * 64 + j) * 64 + k]
                       : Wr[(layer * 64 + j) * 64 + (k - 64)];
    half_t hi = (half_t)v;
    half_t lo = (half_t)(v - (float)hi);
    int f = (s * 4 + t) * 2;
    int base = layer * 16384 + f * 512 + lane * 8 + i;
    Bf[base] = hi;
    Bf[base + 512] = lo;
}

// ---------------- aggregation: groups of 8 lanes, half8 loads, byte-offset gather ----------------
// Every __shfl executes with FULL exec (wave-uniform branches only).

__global__ void kagg(const half_t* __restrict__ h16, const int* __restrict__ rs,
                     const int* __restrict__ soff, half_t* __restrict__ agg16, int N) {
    int w = (blockIdx.x * blockDim.x + threadIdx.x) >> 6;
    int lane = threadIdx.x & 63;
    if (w >= N) return;
    int g = lane >> 3, sub = lane & 7;
    const char* hb = (const char*)h16 + sub * 16;   // lane's column slice base
    int beg = rs[w], end = rs[w + 1];
    const half_t NEG = (half_t)(-65504.0f);
    half8 m0 = {NEG, NEG, NEG, NEG, NEG, NEG, NEG, NEG}, m1 = m0;
    for (int base = beg; base < end; base += 64) {
        int cnt = end - base;
        if (cnt > 64) cnt = 64;
        int sv = (lane < cnt) ? soff[base + lane] : 0;   // coalesced edge read
        int j = 0;
        for (; j + 15 < cnt; j += 16) {
            int o0 = __shfl(sv, j + g);
            int o1 = __shfl(sv, j + 8 + g);
            half8 v0 = *(const half8*)(hb + o0);
            half8 v1 = *(const half8*)(hb + o1);
            m0 = hmax8(m0, v0);
            m1 = hmax8(m1, v1);
        }
        for (; j + 7 < cnt; j += 8) {
            int o0 = __shfl(sv, j + g);
            m0 = hmax8(m0, *(const half8*)(hb + o0));
        }
        if (j < cnt) {                        // wave-uniform branch
            int jg = j + g;
            if (jg >= cnt) jg = cnt - 1;      // clamp: re-max of seen edge is a no-op
            int o0 = __shfl(sv, jg);
            m0 = hmax8(m0, *(const half8*)(hb + o0));
        }
    }
    half8 m = hmax8(m0, m1);
    m = hmax8(m, shfl_xor_h8(m, 8));
    m = hmax8(m, shfl_xor_h8(m, 16));
    m = hmax8(m, shfl_xor_h8(m, 32));
    if (g == 0) {
        if (end <= beg) {
            half8 z = {(half_t)0.f, (half_t)0.f, (half_t)0.f, (half_t)0.f,
                       (half_t)0.f, (half_t)0.f, (half_t)0.f, (half_t)0.f};
            m = z;
        }
        *(half8*)((char*)agg16 + (size_t)w * 128 + sub * 16) = m;
    }
}

// ---------------- fused GEMM: all-fp16 MFMA operands, zero A-side cvt ----------------
// out = agg@Wl + (h_hi+h_lo)@Wr + bias; weights split hi/lo in fp16.

__global__ void __launch_bounds__(256, 2) kgemm(
        const half_t* __restrict__ agg16, const half_t* __restrict__ hhi,
        const half_t* __restrict__ hlo, const half_t* __restrict__ Bf,
        const float* __restrict__ bias, float* __restrict__ out32,
        half_t* __restrict__ ohi, half_t* __restrict__ olo, int N, int last) {
    const int lane = threadIdx.x & 63;
    const int quad = lane >> 4;
    const int lrow = lane & 15;
    const int wv = (blockIdx.x * blockDim.x + threadIdx.x) >> 6;
    const int nwv = (gridDim.x * blockDim.x) >> 6;
    const int ntiles = (N + 15) >> 4;

    // B fragments resident: 32 x half8 = 128 VGPRs
    const half8* __restrict__ Bp = (const half8*)Bf;
    half8 bh[4][4], bl[4][4];
#pragma unroll
    for (int s = 0; s < 4; ++s)
#pragma unroll
        for (int t = 0; t < 4; ++t) {
            int f = (s * 4 + t) * 2;
            bh[s][t] = Bp[f * 64 + lane];
            bl[s][t] = Bp[f * 64 + 64 + lane];
        }

    float bs[4];
#pragma unroll
    for (int t = 0; t < 4; ++t) bs[t] = bias[t * 16 + lrow];

    for (int tile = wv; tile < ntiles; tile += nwv) {
        const int m0 = tile << 4;
        int row = m0 + lrow;
        if (row >= N) row = N - 1;
        const char* pa = (const char*)agg16 + (size_t)row * 128 + quad * 16;
        const char* ph = (const char*)hhi   + (size_t)row * 128 + quad * 16;
        const char* pl = (const char*)hlo   + (size_t)row * 128 + quad * 16;
        half8 Aa0 = *(const half8*)(pa);
        half8 Aa1 = *(const half8*)(pa + 64);
        half8 Hh0 = *(const half8*)(ph);
        half8 Hh1 = *(const half8*)(ph + 64);
        half8 Hl0 = *(const half8*)(pl);
        half8 Hl1 = *(const half8*)(pl + 64);

        f32x4 acc[4] = {{0.f, 0.f, 0.f, 0.f}, {0.f, 0.f, 0.f, 0.f},
                        {0.f, 0.f, 0.f, 0.f}, {0.f, 0.f, 0.f, 0.f}};
#pragma unroll
        for (int t = 0; t < 4; ++t) {
            acc[t] = __builtin_amdgcn_mfma_f32_16x16x32_f16(Aa0, bh[0][t], acc[t], 0, 0, 0);
            acc[t] = __builtin_amdgcn_mfma_f32_16x16x32_f16(Aa0, bl[0][t], acc[t], 0, 0, 0);
            acc[t] = __builtin_amdgcn_mfma_f32_16x16x32_f16(Aa1, bh[1][t], acc[t], 0, 0, 0);
            acc[t] = __builtin_amdgcn_mfma_f32_16x16x32_f16(Aa1, bl[1][t], acc[t], 0, 0, 0);
            acc[t] = __builtin_amdgcn_mfma_f32_16x16x32_f16(Hh0, bh[2][t], acc[t], 0, 0, 0);
            acc[t] = __builtin_amdgcn_mfma_f32_16x16x32_f16(Hl0, bh[2][t], acc[t], 0, 0, 0);
            acc[t] = __builtin_amdgcn_mfma_f32_16x16x32_f16(Hh0, bl[2][t], acc[t], 0, 0, 0);
            acc[t] = __builtin_amdgcn_mfma_f32_16x16x32_f16(Hh1, bh[3][t], acc[t], 0, 0, 0);
            acc[t] = __builtin_amdgcn_mfma_f32_16x16x32_f16(Hl1, bh[3][t], acc[t], 0, 0, 0);
            acc[t] = __builtin_amdgcn_mfma_f32_16x16x32_f16(Hh1, bl[3][t], acc[t], 0, 0, 0);
        }

        // C/D: col = t*16 + (lane&15), row = m0 + quad*4 + r
#pragma unroll
        for (int t = 0; t < 4; ++t) {
            int col = t * 16 + lrow;
#pragma unroll
            for (int r = 0; r < 4; ++r) {
                int orow = m0 + quad * 4 + r;
                if (orow < N) {
                    float v = acc[t][r] + bs[t];
                    if (!last) {
                        v = fmaxf(v, 0.0f);
                        half_t hi = (half_t)v;
                        half_t lo = (half_t)(v - (float)hi);
                        ohi[(size_t)orow * DIM + col] = hi;
                        olo[(size_t)orow * DIM + col] = lo;
                    } else {
                        out32[(size_t)orow * DIM + col] = v;
                    }
                }
            }
        }
    }
}

// ---------------- host ----------------

extern "C" void kernel_launch(void* const* d_in, const int* in_sizes, int n_in,
                              void* d_out, int out_size, void* d_ws, size_t ws_size,
                              hipStream_t stream) {
    const float* x  = (const float*)d_in[0];
    const int*   ei = (const int*)d_in[1];
    const float* Wl = (const float*)d_in[2];
    const float* bl = (const float*)d_in[3];
    const float* Wr = (const float*)d_in[4];
    int N = in_sizes[0] / DIM;
    int E = in_sizes[1] / 2;

    size_t nd = (size_t)N * DIM;
    half_t* p0hi  = (half_t*)d_ws;
    half_t* p0lo  = p0hi + nd;
    half_t* p1hi  = p0lo + nd;
    half_t* p1lo  = p1hi + nd;
    half_t* agg16 = p1lo + nd;               // nd halfs; aliased as `pairs` during CSR build
    int*    rs    = (int*)(agg16 + nd);      // N+1 used, N+4 reserved
    int*    ssrc  = rs + (N + 4);            // byte offsets
    int*    gcnt  = ssrc + E;                // 256
    int*    gbs   = gcnt + 256;              // NB+1 (260 reserved)
    int*    gbc   = gbs + 260;               // 256
    half_t* Bf    = (half_t*)(gbc + 256);    // 6 layers * 16384 halfs

    int NB = (N + 511) >> 9;                 // 196 for N=100000
    int* pairs = (int*)agg16;                // consumed by kfinal before layer 0

    hipMemsetAsync(gcnt, 0, 256 * sizeof(int), stream);
    kbcnt<<<640, 256, 0, stream>>>(ei, E, gcnt);
    kbscan<<<1, 256, 0, stream>>>(gcnt, gbs, gbc, NB, E, rs, N);
    kbin<<<(E + 4095) / 4096, 256, 0, stream>>>(ei, E, gbc, pairs, NB);
    kfinal<<<NB, 256, 0, stream>>>(pairs, gbs, rs, ssrc, N);
    kprepw<<<(6 * 4 * 4 * 64 * 8 + 255) / 256, 256, 0, stream>>>(Wl, Wr, Bf);
    kcvt<<<((int)(nd / 4) + 255) / 256, 256, 0, stream>>>(x, p0hi, p0lo, (int)(nd / 4));

    for (int l = 0; l < 6; ++l) {
        half_t* ihi = (l & 1) ? p1hi : p0hi;
        half_t* ilo = (l & 1) ? p1lo : p0lo;
        half_t* xhi = (l & 1) ? p0hi : p1hi;
        half_t* xlo = (l & 1) ? p0lo : p1lo;
        int last = (l == 5);
        kagg<<<(N + 3) / 4, 256, 0, stream>>>(ihi, rs, ssrc, agg16, N);
        kgemm<<<512, 256, 0, stream>>>(agg16, ihi, ilo, Bf + l * 16384, bl + l * 64,
                                       (float*)d_out, xhi, xlo, N, last);
    }
}

// Round 8
// 461.893 us; speedup vs baseline: 11.7635x; 1.0906x over previous
//
#include <hip/hip_runtime.h>
#include <hip/hip_bf16.h>
#include <math.h>

#define DIM 64

typedef _Float16 half_t;
typedef __attribute__((ext_vector_type(8))) _Float16 half8;
typedef __attribute__((ext_vector_type(4))) _Float16 h16x4;
typedef __attribute__((ext_vector_type(4))) float f32x4;

// v_pk_max_f16 path: llvm.maxnum semantics (NaN-free data, so identical to our max)
__device__ __forceinline__ half8 hmax8(half8 a, half8 b) {
    return __builtin_elementwise_max(a, b);
}
__device__ __forceinline__ half8 shfl_xor_h8(half8 v, int mask) {
    union { half8 h; int i[4]; } u;
    u.h = v;
#pragma unroll
    for (int k = 0; k < 4; ++k) u.i[k] = __shfl_xor(u.i[k], mask);
    return u.h;
}

// ---------------- CSR build (bucket-local; pairs packed src<<9 | dst&511) ----------------

__global__ void kbcnt(const int* __restrict__ ei, int E, int* __restrict__ gcnt) {
    __shared__ int h[256];
    int t = threadIdx.x;
    h[t] = 0;
    __syncthreads();
    for (int e = blockIdx.x * 256 + t; e < E; e += gridDim.x * 256)
        atomicAdd(&h[ei[E + e] >> 9], 1);
    __syncthreads();
    if (h[t]) atomicAdd(&gcnt[t], h[t]);
}

__global__ void kbscan(const int* __restrict__ gcnt, int* __restrict__ gbs,
                       int* __restrict__ gbc, int NB, int E,
                       int* __restrict__ rs, int N) {
    __shared__ int sm[256];
    int t = threadIdx.x;
    int v = (t < NB) ? gcnt[t] : 0;
    sm[t] = v;
    __syncthreads();
    for (int off = 1; off < 256; off <<= 1) {
        int add = (t >= off) ? sm[t - off] : 0;
        __syncthreads();
        sm[t] += add;
        __syncthreads();
    }
    int excl = sm[t] - v;
    if (t < NB) { gbs[t] = excl; gbc[t] = excl; }
    if (t == NB - 1) gbs[NB] = excl + v;    // == E
    if (t == 0) rs[N] = E;
}

__global__ void kbin(const int* __restrict__ ei, int E,
                     int* __restrict__ gbc, int* __restrict__ pairs, int NB) {
    __shared__ int hist[256];
    __shared__ int basep[256];
    const int t = threadIdx.x;
    const int c0 = blockIdx.x * 4096;
    hist[t] = 0;
    __syncthreads();
    int s[16], d[16];
#pragma unroll
    for (int i = 0; i < 16; ++i) {
        int e = c0 + i * 256 + t;
        if (e < E) {
            s[i] = ei[e];
            d[i] = ei[E + e];
            atomicAdd(&hist[d[i] >> 9], 1);
        } else d[i] = -1;
    }
    __syncthreads();
    if (t < NB) {
        basep[t] = atomicAdd(&gbc[t], hist[t]);
        hist[t] = 0;
    }
    __syncthreads();
#pragma unroll
    for (int i = 0; i < 16; ++i) {
        if (d[i] >= 0) {
            int b = d[i] >> 9;
            int off = atomicAdd(&hist[b], 1);
            pairs[basep[b] + off] = (s[i] << 9) | (d[i] & 511);
        }
    }
}

// ssrc stores BYTE offsets (src * 128) for the fp16 row gather.
__global__ void __launch_bounds__(256) kfinal(
        const int* __restrict__ pairs, const int* __restrict__ gbs,
        int* __restrict__ rs, int* __restrict__ ssrc, int N) {
    __shared__ int lcnt[512];
    __shared__ int lcur[512];
    __shared__ int ps[256];
    const int b = blockIdx.x;
    const int t = threadIdx.x;
    const int n0 = b << 9;
    const int e0 = gbs[b], e1 = gbs[b + 1];
    lcnt[t] = 0;
    lcnt[t + 256] = 0;
    __syncthreads();
    for (int e = e0 + t; e < e1; e += 256)
        atomicAdd(&lcnt[pairs[e] & 511], 1);
    __syncthreads();
    int c0 = lcnt[2 * t], c1 = lcnt[2 * t + 1];
    int sum = c0 + c1;
    ps[t] = sum;
    __syncthreads();
    for (int off = 1; off < 256; off <<= 1) {
        int add = (t >= off) ? ps[t - off] : 0;
        __syncthreads();
        ps[t] += add;
        __syncthreads();
    }
    int excl = ps[t] - sum;
    lcur[2 * t] = excl;
    lcur[2 * t + 1] = excl + c0;
    int n = n0 + 2 * t;
    if (n < N) rs[n] = e0 + excl;
    if (n + 1 < N) rs[n + 1] = e0 + excl + c0;
    __syncthreads();
    for (int e = e0 + t; e < e1; e += 256) {
        int p = pairs[e];
        int pos = atomicAdd(&lcur[p & 511], 1);
        ssrc[e0 + pos] = (int)((unsigned)p >> 9) << 7;   // byte offset of fp16 row
    }
}

// ---------------- fp32 x -> fp16 hi/lo planes ----------------

__global__ void kcvt(const float* __restrict__ x, half_t* __restrict__ phi,
                     half_t* __restrict__ plo, int n4) {
    int i = blockIdx.x * blockDim.x + threadIdx.x;
    if (i < n4) {
        f32x4 v = ((const f32x4*)x)[i];
        h16x4 hi, lo;
#pragma unroll
        for (int c = 0; c < 4; ++c) {
            hi[c] = (half_t)v[c];
            lo[c] = (half_t)(v[c] - (float)hi[c]);
        }
        ((h16x4*)phi)[i] = hi;
        ((h16x4*)plo)[i] = lo;
    }
}

// ---------------- weight prep: fp16 hi/lo MFMA B-fragments ----------------

__global__ void kprepw(const float* __restrict__ Wl, const float* __restrict__ Wr,
                       half_t* __restrict__ Bf) {
    int id = blockIdx.x * blockDim.x + threadIdx.x;
    if (id >= 6 * 4 * 4 * 64 * 8) return;
    int i = id & 7;
    int lane = (id >> 3) & 63;
    int t = (id >> 9) & 3;
    int s = (id >> 11) & 3;
    int layer = id >> 13;
    int k = s * 32 + (lane >> 4) * 8 + i;
    int j = t * 16 + (lane & 15);
    float v = (k < 64) ? Wl[(layer * 64 + j) * 64 + k]
                       : Wr[(layer * 64 + j) * 64 + (k - 64)];
    half_t hi = (half_t)v;
    half_t lo = (half_t)(v - (float)hi);
    int f = (s * 4 + t) * 2;
    int base = layer * 16384 + f * 512 + lane * 8 + i;
    Bf[base] = hi;
    Bf[base + 512] = lo;
}

// ---------------- aggregation: groups of 8 lanes, half8 loads, byte-offset gather ----------------
// Every __shfl executes with FULL exec (wave-uniform branches only).

__global__ void kagg(const half_t* __restrict__ h16, const int* __restrict__ rs,
                     const int* __restrict__ soff, half_t* __restrict__ agg16, int N) {
    int w = (blockIdx.x * blockDim.x + threadIdx.x) >> 6;
    int lane = threadIdx.x & 63;
    if (w >= N) return;
    int g = lane >> 3, sub = lane & 7;
    const char* hb = (const char*)h16 + sub * 16;   // lane's column slice base
    int beg = rs[w], end = rs[w + 1];
    const half_t NEG = (half_t)(-65504.0f);
    half8 m0 = {NEG, NEG, NEG, NEG, NEG, NEG, NEG, NEG}, m1 = m0;
    for (int base = beg; base < end; base += 64) {
        int cnt = end - base;
        if (cnt > 64) cnt = 64;
        int sv = (lane < cnt) ? soff[base + lane] : 0;   // coalesced edge read
        int j = 0;
        for (; j + 15 < cnt; j += 16) {
            int o0 = __shfl(sv, j + g);
            int o1 = __shfl(sv, j + 8 + g);
            half8 v0 = *(const half8*)(hb + o0);
            half8 v1 = *(const half8*)(hb + o1);
            m0 = hmax8(m0, v0);
            m1 = hmax8(m1, v1);
        }
        for (; j + 7 < cnt; j += 8) {
            int o0 = __shfl(sv, j + g);
            m0 = hmax8(m0, *(const half8*)(hb + o0));
        }
        if (j < cnt) {                        // wave-uniform branch
            int jg = j + g;
            if (jg >= cnt) jg = cnt - 1;      // clamp: re-max of seen edge is a no-op
            int o0 = __shfl(sv, jg);
            m0 = hmax8(m0, *(const half8*)(hb + o0));
        }
    }
    half8 m = hmax8(m0, m1);
    m = hmax8(m, shfl_xor_h8(m, 8));
    m = hmax8(m, shfl_xor_h8(m, 16));
    m = hmax8(m, shfl_xor_h8(m, 32));
    if (g == 0) {
        if (end <= beg) {
            half8 z = {(half_t)0.f, (half_t)0.f, (half_t)0.f, (half_t)0.f,
                       (half_t)0.f, (half_t)0.f, (half_t)0.f, (half_t)0.f};
            m = z;
        }
        *(half8*)((char*)agg16 + (size_t)w * 128 + sub * 16) = m;
    }
}

// ---------------- fused GEMM: all-fp16 MFMA operands, zero A-side cvt ----------------

__global__ void __launch_bounds__(256, 2) kgemm(
        const half_t* __restrict__ agg16, const half_t* __restrict__ hhi,
        const half_t* __restrict__ hlo, const half_t* __restrict__ Bf,
        const float* __restrict__ bias, float* __restrict__ out32,
        half_t* __restrict__ ohi, half_t* __restrict__ olo, int N, int last) {
    const int lane = threadIdx.x & 63;
    const int quad = lane >> 4;
    const int lrow = lane & 15;
    const int wv = (blockIdx.x * blockDim.x + threadIdx.x) >> 6;
    const int nwv = (gridDim.x * blockDim.x) >> 6;
    const int ntiles = (N + 15) >> 4;

    const half8* __restrict__ Bp = (const half8*)Bf;
    half8 bh[4][4], bl[4][4];
#pragma unroll
    for (int s = 0; s < 4; ++s)
#pragma unroll
        for (int t = 0; t < 4; ++t) {
            int f = (s * 4 + t) * 2;
            bh[s][t] = Bp[f * 64 + lane];
            bl[s][t] = Bp[f * 64 + 64 + lane];
        }

    float bs[4];
#pragma unroll
    for (int t = 0; t < 4; ++t) bs[t] = bias[t * 16 + lrow];

    for (int tile = wv; tile < ntiles; tile += nwv) {
        const int m0 = tile << 4;
        int row = m0 + lrow;
        if (row >= N) row = N - 1;
        const char* pa = (const char*)agg16 + (size_t)row * 128 + quad * 16;
        const char* ph = (const char*)hhi   + (size_t)row * 128 + quad * 16;
        const char* pl = (const char*)hlo   + (size_t)row * 128 + quad * 16;
        half8 Aa0 = *(const half8*)(pa);
        half8 Aa1 = *(const half8*)(pa + 64);
        half8 Hh0 = *(const half8*)(ph);
        half8 Hh1 = *(const half8*)(ph + 64);
        half8 Hl0 = *(const half8*)(pl);
        half8 Hl1 = *(const half8*)(pl + 64);

        f32x4 acc[4] = {{0.f, 0.f, 0.f, 0.f}, {0.f, 0.f, 0.f, 0.f},
                        {0.f, 0.f, 0.f, 0.f}, {0.f, 0.f, 0.f, 0.f}};
#pragma unroll
        for (int t = 0; t < 4; ++t) {
            acc[t] = __builtin_amdgcn_mfma_f32_16x16x32_f16(Aa0, bh[0][t], acc[t], 0, 0, 0);
            acc[t] = __builtin_amdgcn_mfma_f32_16x16x32_f16(Aa0, bl[0][t], acc[t], 0, 0, 0);
            acc[t] = __builtin_amdgcn_mfma_f32_16x16x32_f16(Aa1, bh[1][t], acc[t], 0, 0, 0);
            acc[t] = __builtin_amdgcn_mfma_f32_16x16x32_f16(Aa1, bl[1][t], acc[t], 0, 0, 0);
            acc[t] = __builtin_amdgcn_mfma_f32_16x16x32_f16(Hh0, bh[2][t], acc[t], 0, 0, 0);
            acc[t] = __builtin_amdgcn_mfma_f32_16x16x32_f16(Hl0, bh[2][t], acc[t], 0, 0, 0);
            acc[t] = __builtin_amdgcn_mfma_f32_16x16x32_f16(Hh0, bl[2][t], acc[t], 0, 0, 0);
            acc[t] = __builtin_amdgcn_mfma_f32_16x16x32_f16(Hh1, bh[3][t], acc[t], 0, 0, 0);
            acc[t] = __builtin_amdgcn_mfma_f32_16x16x32_f16(Hl1, bh[3][t], acc[t], 0, 0, 0);
            acc[t] = __builtin_amdgcn_mfma_f32_16x16x32_f16(Hh1, bl[3][t], acc[t], 0, 0, 0);
        }

#pragma unroll
        for (int t = 0; t < 4; ++t) {
            int col = t * 16 + lrow;
#pragma unroll
            for (int r = 0; r < 4; ++r) {
                int orow = m0 + quad * 4 + r;
                if (orow < N) {
                    float v = acc[t][r] + bs[t];
                    if (!last) {
                        v = fmaxf(v, 0.0f);
                        half_t hi = (half_t)v;
                        half_t lo = (half_t)(v - (float)hi);
                        ohi[(size_t)orow * DIM + col] = hi;
                        olo[(size_t)orow * DIM + col] = lo;
                    } else {
                        out32[(size_t)orow * DIM + col] = v;
                    }
                }
            }
        }
    }
}

// ---------------- host ----------------

extern "C" void kernel_launch(void* const* d_in, const int* in_sizes, int n_in,
                              void* d_out, int out_size, void* d_ws, size_t ws_size,
                              hipStream_t stream) {
    const float* x  = (const float*)d_in[0];
    const int*   ei = (const int*)d_in[1];
    const float* Wl = (const float*)d_in[2];
    const float* bl = (const float*)d_in[3];
    const float* Wr = (const float*)d_in[4];
    int N = in_sizes[0] / DIM;
    int E = in_sizes[1] / 2;

    size_t nd = (size_t)N * DIM;
    half_t* p0hi  = (half_t*)d_ws;
    half_t* p0lo  = p0hi + nd;
    half_t* p1hi  = p0lo + nd;
    half_t* p1lo  = p1hi + nd;
    half_t* agg16 = p1lo + nd;               // nd halfs; aliased as `pairs` during CSR build
    int*    rs    = (int*)(agg16 + nd);      // N+1 used, N+4 reserved
    int*    ssrc  = rs + (N + 4);            // byte offsets
    int*    gcnt  = ssrc + E;                // 256
    int*    gbs   = gcnt + 256;              // NB+1 (260 reserved)
    int*    gbc   = gbs + 260;               // 256
    half_t* Bf    = (half_t*)(gbc + 256);    // 6 layers * 16384 halfs

    int NB = (N + 511) >> 9;                 // 196 for N=100000
    int* pairs = (int*)agg16;                // consumed by kfinal before layer 0

    hipMemsetAsync(gcnt, 0, 256 * sizeof(int), stream);
    kbcnt<<<640, 256, 0, stream>>>(ei, E, gcnt);
    kbscan<<<1, 256, 0, stream>>>(gcnt, gbs, gbc, NB, E, rs, N);
    kbin<<<(E + 4095) / 4096, 256, 0, stream>>>(ei, E, gbc, pairs, NB);
    kfinal<<<NB, 256, 0, stream>>>(pairs, gbs, rs, ssrc, N);
    kprepw<<<(6 * 4 * 4 * 64 * 8 + 255) / 256, 256, 0, stream>>>(Wl, Wr, Bf);
    kcvt<<<((int)(nd / 4) + 255) / 256, 256, 0, stream>>>(x, p0hi, p0lo, (int)(nd / 4));

    for (int l = 0; l < 6; ++l) {
        half_t* ihi = (l & 1) ? p1hi : p0hi;
        half_t* ilo = (l & 1) ? p1lo : p0lo;
        half_t* xhi = (l & 1) ? p0hi : p1hi;
        half_t* xlo = (l & 1) ? p0lo : p1lo;
        int last = (l == 5);
        kagg<<<(N + 3) / 4, 256, 0, stream>>>(ihi, rs, ssrc, agg16, N);
        kgemm<<<512, 256, 0, stream>>>(agg16, ihi, ilo, Bf + l * 16384, bl + l * 64,
                                       (float*)d_out, xhi, xlo, N, last);
    }
}